// Round 12
// baseline (1037.036 us; speedup 1.0000x reference)
//
#include <hip/hip_runtime.h>
#include <hip/hip_bf16.h>
#include <math.h>

#define TT 64
#define NN 2000
#define FIN 32
#define HH 64
#define CC 10
#define EE 32000
#define ETOT 34000   // E + N self loops
#define THL 4096     // T*H
#define EPSBN 1e-5f

// ---------------- workspace layout (float offsets) ----------------
#define OFF_WC   0u          // WCh bf16 [2048][2048]
#define OFF_XA   4000000u    // 8,192,000  [N,T,H] fp32
#define OFF_XB   12192000u   // 8,192,000  (x_agg fp32)
#define OFF_XC   20384000u   // 8,192,000  (first: XAh_t bf16 [4096][2048]; then fusion out fp32)
#define OFF_DEG  28576000u   // 2048
#define OFF_H1   28578048u   // 128,000 (unused)
#define OFF_CNT  28706048u   // int 2048
#define OFF_CUR  28708096u   // int 2048
#define OFF_OFF  28710144u   // int 2064
#define OFF_CSRS 28712208u   // int 34016
#define OFF_CSRN 28746224u   // float 34016
#define OFF_HST  28780240u   // float 128,000  (GRU h-state)

typedef __attribute__((ext_vector_type(8))) short short8v;
typedef __attribute__((ext_vector_type(4))) float f32x4;

__device__ __forceinline__ float fsigmoid(float x) { return 1.f / (1.f + __expf(-x)); }
__device__ __forceinline__ unsigned short f2bf(float f) {
    __hip_bfloat16 h = __float2bfloat16(f);
    return *reinterpret_cast<unsigned short*>(&h);
}

// ---------------- CSR build ----------------
__global__ void k_zero(int* cnt, int* cur, float* deg) {
    int i = blockIdx.x * 256 + threadIdx.x;
    if (i < 2048) { cnt[i] = 0; cur[i] = 0; deg[i] = 0.f; }
}

__global__ void k_count(const int* __restrict__ ei, const float* __restrict__ ew,
                        int* cnt, float* deg) {
    int e = blockIdx.x * 256 + threadIdx.x;
    if (e < ETOT) {
        int dst; float w;
        if (e < EE) { dst = ei[EE + e]; w = ew[e]; }
        else        { dst = e - EE;     w = 1.f; }
        atomicAdd(&cnt[dst], 1);
        atomicAdd(&deg[dst], w);
    }
}

__global__ __launch_bounds__(1024) void k_scan(const int* __restrict__ cnt, int* off) {
    __shared__ int s[2048];
    int tid = threadIdx.x;
    s[tid]        = (tid        < NN) ? cnt[tid]        : 0;
    s[tid + 1024] = (tid + 1024 < NN) ? cnt[tid + 1024] : 0;
    __syncthreads();
    for (int d = 1; d < 2048; d <<= 1) {
        int idx = (tid + 1) * (d << 1) - 1;
        if (idx < 2048) s[idx] += s[idx - d];
        __syncthreads();
    }
    if (tid == 0) s[2047] = 0;
    __syncthreads();
    for (int d = 1024; d >= 1; d >>= 1) {
        int idx = (tid + 1) * (d << 1) - 1;
        if (idx < 2048) { int t = s[idx - d]; s[idx - d] = s[idx]; s[idx] += t; }
        __syncthreads();
    }
    off[tid] = s[tid];
    off[tid + 1024] = s[tid + 1024];
}

__global__ void k_fill(const int* __restrict__ ei, const float* __restrict__ ew,
                       const float* __restrict__ deg, const int* __restrict__ off,
                       int* cur, int* csr_src, float* csr_nrm) {
    int e = blockIdx.x * 256 + threadIdx.x;
    if (e < ETOT) {
        int src, dst; float w;
        if (e < EE) { src = ei[e]; dst = ei[EE + e]; w = ew[e]; }
        else        { src = dst = e - EE;            w = 1.f; }
        float ds = rsqrtf(fmaxf(deg[src], 1e-12f));
        float dd = rsqrtf(fmaxf(deg[dst], 1e-12f));
        int pos = off[dst] + atomicAdd(&cur[dst], 1);
        csr_src[pos] = src;
        csr_nrm[pos] = ds * w * dd;
    }
}

// ---------------- softmax over causal_weight rows -> bf16 WCh [2048 stride] ----------------
__global__ __launch_bounds__(256) void k_softmax(const float* __restrict__ CW,
                                                 unsigned short* __restrict__ WCH) {
    __shared__ float row[NN];
    __shared__ float red[256];
    int r = blockIdx.x, tid = threadIdx.x;
    const float* in = CW + (size_t)r * NN;
    float mx = -1e30f;
    for (int i = tid; i < NN; i += 256) { float v = in[i]; row[i] = v; mx = fmaxf(mx, v); }
    red[tid] = mx; __syncthreads();
    for (int s = 128; s > 0; s >>= 1) {
        if (tid < s) red[tid] = fmaxf(red[tid], red[tid + s]);
        __syncthreads();
    }
    mx = red[0]; __syncthreads();
    float sm = 0.f;
    for (int i = tid; i < NN; i += 256) { float e = __expf(row[i] - mx); row[i] = e; sm += e; }
    red[tid] = sm; __syncthreads();
    for (int s = 128; s > 0; s >>= 1) {
        if (tid < s) red[tid] += red[tid + s];
        __syncthreads();
    }
    float inv = 1.f / red[0];
    unsigned short* out = WCH + (size_t)r * 2048;
    for (int i = tid; i < 2048; i += 256)
        out[i] = (i < NN) ? f2bf(row[i] * inv) : (unsigned short)0;
}

// ---------------- lin_in as tiled GEMM: rows=(n,t), K=32, 64 cols ----------------
__global__ __launch_bounds__(256) void k_lin2(const float* __restrict__ XS,
                                              const float* __restrict__ W,
                                              const float* __restrict__ b,
                                              float* __restrict__ OUT) {
    __shared__ float Wt[FIN][68];   // [k][o]
    __shared__ float As[FIN][68];   // [k][row]
    int tid = threadIdx.x;
    int n = blockIdx.x;
    for (int i = tid; i < HH * FIN; i += 256) { int o = i >> 5, k = i & 31; Wt[k][o] = W[i]; }
    int row = tid >> 2, kq = tid & 3;   // row = t
    {
        const float4* src = (const float4*)(XS + ((size_t)row * NN + n) * FIN + kq * 8);
        float4 v0 = src[0], v1 = src[1];
        As[kq * 8 + 0][row] = v0.x; As[kq * 8 + 1][row] = v0.y;
        As[kq * 8 + 2][row] = v0.z; As[kq * 8 + 3][row] = v0.w;
        As[kq * 8 + 4][row] = v1.x; As[kq * 8 + 5][row] = v1.y;
        As[kq * 8 + 6][row] = v1.z; As[kq * 8 + 7][row] = v1.w;
    }
    __syncthreads();
    int tx = tid & 15, ty = tid >> 4;
    float acc[4][4] = {};
#pragma unroll
    for (int k = 0; k < FIN; ++k) {
        float4 av = *(const float4*)&As[k][ty * 4];
        float4 wv = *(const float4*)&Wt[k][tx * 4];
        acc[0][0] += av.x * wv.x; acc[0][1] += av.x * wv.y; acc[0][2] += av.x * wv.z; acc[0][3] += av.x * wv.w;
        acc[1][0] += av.y * wv.x; acc[1][1] += av.y * wv.y; acc[1][2] += av.y * wv.z; acc[1][3] += av.y * wv.w;
        acc[2][0] += av.z * wv.x; acc[2][1] += av.z * wv.y; acc[2][2] += av.z * wv.z; acc[2][3] += av.z * wv.w;
        acc[3][0] += av.w * wv.x; acc[3][1] += av.w * wv.y; acc[3][2] += av.w * wv.z; acc[3][3] += av.w * wv.w;
    }
    float4 bv = *(const float4*)(b + tx * 4);
#pragma unroll
    for (int ii = 0; ii < 4; ++ii) {
        float4 o;
        o.x = fmaxf(acc[ii][0] + bv.x, 0.f);
        o.y = fmaxf(acc[ii][1] + bv.y, 0.f);
        o.z = fmaxf(acc[ii][2] + bv.z, 0.f);
        o.w = fmaxf(acc[ii][3] + bv.w, 0.f);
        *(float4*)(OUT + ((size_t)n * TT + ty * 4 + ii) * HH + tx * 4) = o;
    }
}

// ---------------- transpose + bf16 cast ----------------
__global__ __launch_bounds__(256) void k_tr(const float* __restrict__ X,
                                            unsigned short* __restrict__ XT) {
    __shared__ unsigned short tile[64][65];
    int cb = blockIdx.x * 64;
    int kb = blockIdx.y * 64;
    int tid = threadIdx.x;
    int r = tid >> 2, cq = tid & 3;
    const float4* src = (const float4*)(X + (size_t)(kb + r) * THL + cb + cq * 16);
#pragma unroll
    for (int j = 0; j < 4; ++j) {
        float4 v = src[j];
        tile[cq * 16 + j * 4 + 0][r] = f2bf(v.x);
        tile[cq * 16 + j * 4 + 1][r] = f2bf(v.y);
        tile[cq * 16 + j * 4 + 2][r] = f2bf(v.z);
        tile[cq * 16 + j * 4 + 3][r] = f2bf(v.w);
    }
    __syncthreads();
    int cl = tid >> 2, kq = tid & 3;
    unsigned short tmp[16];
#pragma unroll
    for (int j = 0; j < 16; ++j) tmp[j] = tile[cl][kq * 16 + j];
    unsigned short* dst = XT + (size_t)(cb + cl) * 2048 + kb + kq * 16;
    *(uint4*)dst = *(uint4*)tmp;
    *(uint4*)(dst + 8) = *(uint4*)(tmp + 8);
}

// ---------------- bf16 MFMA GEMM: C[2000,4096] = WCh @ X (via XAh_t) ----------------
__global__ __launch_bounds__(256, 1) void k_gemm_bf(const unsigned short* __restrict__ A,
                                                    const unsigned short* __restrict__ B,
                                                    float* __restrict__ C) {
    __shared__ unsigned short As[128][72];
    __shared__ unsigned short Bs[128][72];
    int tid = threadIdx.x;
    int mb = blockIdx.y * 128, nb = blockIdx.x * 128;
    int w = tid >> 6, lane = tid & 63;
    int wr = w >> 1, wc = w & 1;
    int l15 = lane & 15, l4 = lane >> 4;
    f32x4 acc[4][4] = {};
    int arow = tid >> 3, acol = tid & 7;   // 8 threads per row, 16B each
    const uint4* ga = (const uint4*)(A + (size_t)(mb + arow) * 2048 + acol * 8);
    const uint4* gb = (const uint4*)(B + (size_t)(nb + arow) * 2048 + acol * 8);
    uint4 va[4], vb[4];
#pragma unroll
    for (int i = 0; i < 4; ++i) { va[i] = ga[(size_t)i * 8192]; vb[i] = gb[(size_t)i * 8192]; }
    ga += 8; gb += 8;
    for (int kt = 0; kt < 32; ++kt) {
        __syncthreads();
#pragma unroll
        for (int i = 0; i < 4; ++i) {
            *(uint4*)&As[arow + i * 32][acol * 8] = va[i];
            *(uint4*)&Bs[arow + i * 32][acol * 8] = vb[i];
        }
        __syncthreads();
        if (kt < 31) {
#pragma unroll
            for (int i = 0; i < 4; ++i) { va[i] = ga[(size_t)i * 8192]; vb[i] = gb[(size_t)i * 8192]; }
            ga += 8; gb += 8;
        }
#pragma unroll
        for (int kk = 0; kk < 2; ++kk) {
            short8v af[4], bfr[4];
#pragma unroll
            for (int f = 0; f < 4; ++f) {
                af[f]  = *(const short8v*)&As[wr * 64 + f * 16 + l15][kk * 32 + l4 * 8];
                bfr[f] = *(const short8v*)&Bs[wc * 64 + f * 16 + l15][kk * 32 + l4 * 8];
            }
#pragma unroll
            for (int fm = 0; fm < 4; ++fm)
#pragma unroll
                for (int fn = 0; fn < 4; ++fn)
                    acc[fm][fn] = __builtin_amdgcn_mfma_f32_16x16x32_bf16(af[fm], bfr[fn], acc[fm][fn], 0, 0, 0);
        }
    }
    // epilogue: LDS transpose -> 256B-contiguous-per-row stores
    float* epi = (float*)(&As[0][0]) + (size_t)w * (16 * 68);
    int erow4 = lane >> 4;
    int ecol  = lane & 15;
#pragma unroll
    for (int fm = 0; fm < 4; ++fm) {
        __syncthreads();
#pragma unroll
        for (int fn = 0; fn < 4; ++fn)
#pragma unroll
            for (int rr = 0; rr < 4; ++rr)
                epi[(l4 * 4 + rr) * 68 + fn * 16 + l15] = acc[fm][fn][rr];
        __syncthreads();
#pragma unroll
        for (int rr = 0; rr < 4; ++rr) {
            int grow = mb + wr * 64 + fm * 16 + rr * 4 + erow4;
            if (grow < NN) {
                *(float4*)(C + (size_t)grow * THL + nb + wc * 64 + ecol * 4)
                    = *(const float4*)&epi[(rr * 4 + erow4) * 68 + ecol * 4];
            }
        }
    }
}

// ---------------- fusion as tiled GEMM: K=128 (two 64-K phases), 64 cols ----------------
__global__ __launch_bounds__(256) void k_fus2(const float* __restrict__ X,
                                              const float* __restrict__ XAgg,
                                              const float* __restrict__ W,
                                              const float* __restrict__ b,
                                              float* __restrict__ OUT) {
    __shared__ float Wt[2 * HH][68];  // [k][o], k = 0..127
    __shared__ float As[HH][68];      // [k][row]
    int tid = threadIdx.x;
    size_t r0 = (size_t)blockIdx.x * 64;
    for (int i = tid; i < HH * 2 * HH; i += 256) { int o = i >> 7, k = i & 127; Wt[k][o] = W[i]; }
    int row = tid >> 2, kq = tid & 3;
    int tx = tid & 15, ty = tid >> 4;
    float acc[4][4] = {};
    const float* srcs[2] = { X, XAgg };
#pragma unroll
    for (int ph = 0; ph < 2; ++ph) {
        __syncthreads();
        const float4* src = (const float4*)(srcs[ph] + (r0 + row) * HH + kq * 16);
#pragma unroll
        for (int j = 0; j < 4; ++j) {
            float4 v = src[j];
            As[kq * 16 + j * 4 + 0][row] = v.x;
            As[kq * 16 + j * 4 + 1][row] = v.y;
            As[kq * 16 + j * 4 + 2][row] = v.z;
            As[kq * 16 + j * 4 + 3][row] = v.w;
        }
        __syncthreads();
#pragma unroll
        for (int k = 0; k < HH; ++k) {
            float4 av = *(const float4*)&As[k][ty * 4];
            float4 wv = *(const float4*)&Wt[ph * HH + k][tx * 4];
            acc[0][0] += av.x * wv.x; acc[0][1] += av.x * wv.y; acc[0][2] += av.x * wv.z; acc[0][3] += av.x * wv.w;
            acc[1][0] += av.y * wv.x; acc[1][1] += av.y * wv.y; acc[1][2] += av.y * wv.z; acc[1][3] += av.y * wv.w;
            acc[2][0] += av.z * wv.x; acc[2][1] += av.z * wv.y; acc[2][2] += av.z * wv.z; acc[2][3] += av.z * wv.w;
            acc[3][0] += av.w * wv.x; acc[3][1] += av.w * wv.y; acc[3][2] += av.w * wv.z; acc[3][3] += av.w * wv.w;
        }
    }
    float4 bv = *(const float4*)(b + tx * 4);
#pragma unroll
    for (int ii = 0; ii < 4; ++ii) {
        float4 o;
        o.x = fmaxf(acc[ii][0] + bv.x, 0.f);
        o.y = fmaxf(acc[ii][1] + bv.y, 0.f);
        o.z = fmaxf(acc[ii][2] + bv.z, 0.f);
        o.w = fmaxf(acc[ii][3] + bv.w, 0.f);
        *(float4*)(OUT + (r0 + ty * 4 + ii) * HH + tx * 4) = o;
    }
}

// ---------------- GCN xw as tiled GEMM: K=64, 64 cols, no bias ----------------
__global__ __launch_bounds__(256) void k_xw2(const float* __restrict__ IN,
                                             const float* __restrict__ W,
                                             float* __restrict__ OUT) {
    __shared__ float Wt[HH][68];
    __shared__ float As[HH][68];
    int tid = threadIdx.x;
    size_t r0 = (size_t)blockIdx.x * 64;
    for (int i = tid; i < HH * HH; i += 256) { int o = i >> 6, k = i & 63; Wt[k][o] = W[i]; }
    int row = tid >> 2, kq = tid & 3;
    {
        const float4* src = (const float4*)(IN + (r0 + row) * HH + kq * 16);
#pragma unroll
        for (int j = 0; j < 4; ++j) {
            float4 v = src[j];
            As[kq * 16 + j * 4 + 0][row] = v.x;
            As[kq * 16 + j * 4 + 1][row] = v.y;
            As[kq * 16 + j * 4 + 2][row] = v.z;
            As[kq * 16 + j * 4 + 3][row] = v.w;
        }
    }
    __syncthreads();
    int tx = tid & 15, ty = tid >> 4;
    float acc[4][4] = {};
#pragma unroll
    for (int k = 0; k < HH; ++k) {
        float4 av = *(const float4*)&As[k][ty * 4];
        float4 wv = *(const float4*)&Wt[k][tx * 4];
        acc[0][0] += av.x * wv.x; acc[0][1] += av.x * wv.y; acc[0][2] += av.x * wv.z; acc[0][3] += av.x * wv.w;
        acc[1][0] += av.y * wv.x; acc[1][1] += av.y * wv.y; acc[1][2] += av.y * wv.z; acc[1][3] += av.y * wv.w;
        acc[2][0] += av.z * wv.x; acc[2][1] += av.z * wv.y; acc[2][2] += av.z * wv.z; acc[2][3] += av.z * wv.w;
        acc[3][0] += av.w * wv.x; acc[3][1] += av.w * wv.y; acc[3][2] += av.w * wv.z; acc[3][3] += av.w * wv.w;
    }
#pragma unroll
    for (int ii = 0; ii < 4; ++ii) {
        float4 o = make_float4(acc[ii][0], acc[ii][1], acc[ii][2], acc[ii][3]);
        *(float4*)(OUT + (r0 + ty * 4 + ii) * HH + tx * 4) = o;
    }
}

// ---------------- GCN aggregate (CSR) + bias + BN + relu, column-chunked ----------------
__global__ __launch_bounds__(256) void k_agg(const float* __restrict__ XW,
                                             const int* __restrict__ off,
                                             const int* __restrict__ csr_src,
                                             const float* __restrict__ csr_nrm,
                                             const float* __restrict__ bias,
                                             const float* __restrict__ g,
                                             const float* __restrict__ bb,
                                             const float* __restrict__ m,
                                             const float* __restrict__ v,
                                             float* __restrict__ OUT) {
    int dst = blockIdx.x, ch = blockIdx.y, tid = threadIdx.x;
    int base = ch * 1024 + tid * 4;
    float4 acc = make_float4(0.f, 0.f, 0.f, 0.f);
    int beg = off[dst], end = off[dst + 1];
    for (int e = beg; e < end; ++e) {
        int src = csr_src[e];
        float w = csr_nrm[e];
        float4 x = *(const float4*)(XW + (size_t)src * THL + base);
        acc.x += w * x.x; acc.y += w * x.y; acc.z += w * x.z; acc.w += w * x.w;
    }
    int h0 = base & 63;
    float4 bs = *(const float4*)(bias + h0);
    float4 gv = *(const float4*)(g + h0);
    float4 vv = *(const float4*)(v + h0);
    float4 mv = *(const float4*)(m + h0);
    float4 bv = *(const float4*)(bb + h0);
    float4 o;
    o.x = fmaxf((acc.x + bs.x - mv.x) * rsqrtf(vv.x + EPSBN) * gv.x + bv.x, 0.f);
    o.y = fmaxf((acc.y + bs.y - mv.y) * rsqrtf(vv.y + EPSBN) * gv.y + bv.y, 0.f);
    o.z = fmaxf((acc.z + bs.z - mv.z) * rsqrtf(vv.z + EPSBN) * gv.z + bv.z, 0.f);
    o.w = fmaxf((acc.w + bs.w - mv.w) * rsqrtf(vv.w + EPSBN) * gv.w + bv.w, 0.f);
    *(float4*)(OUT + (size_t)dst * THL + base) = o;
}

// ---------------- fused full-T GRU layer: one wave per node ----------------
// Lane j owns h[j] plus ALL SIX weight rows {wih,whh} x {r,z,n}[j] in 384 VGPRs.
// x_t and h broadcast via readlane (6 independent FMA chains, ILP-6).
// Replaces 16 k_gi2 + 16 k_rec dispatches and the 394MB GI round-trip.
__global__ __launch_bounds__(64, 1) void k_gruL(const float* __restrict__ IN,
                                                const float* __restrict__ wih,
                                                const float* __restrict__ whh,
                                                const float* __restrict__ bih,
                                                const float* __restrict__ bhh,
                                                float* __restrict__ hout,
                                                float* __restrict__ yout) {
    int j = threadIdx.x;
    int n = blockIdx.x;
    float wxr[64], wxz[64], wxn[64], whr[64], whz[64], whn[64];
    const float4* wi4 = (const float4*)wih;
    const float4* wh4 = (const float4*)whh;
#pragma unroll
    for (int q = 0; q < 16; ++q) {
        float4 a = wi4[(size_t)j * 16 + q];
        float4 b = wi4[(size_t)(64 + j) * 16 + q];
        float4 c = wi4[(size_t)(128 + j) * 16 + q];
        wxr[4 * q + 0] = a.x; wxr[4 * q + 1] = a.y; wxr[4 * q + 2] = a.z; wxr[4 * q + 3] = a.w;
        wxz[4 * q + 0] = b.x; wxz[4 * q + 1] = b.y; wxz[4 * q + 2] = b.z; wxz[4 * q + 3] = b.w;
        wxn[4 * q + 0] = c.x; wxn[4 * q + 1] = c.y; wxn[4 * q + 2] = c.z; wxn[4 * q + 3] = c.w;
        float4 d = wh4[(size_t)j * 16 + q];
        float4 e = wh4[(size_t)(64 + j) * 16 + q];
        float4 f = wh4[(size_t)(128 + j) * 16 + q];
        whr[4 * q + 0] = d.x; whr[4 * q + 1] = d.y; whr[4 * q + 2] = d.z; whr[4 * q + 3] = d.w;
        whz[4 * q + 0] = e.x; whz[4 * q + 1] = e.y; whz[4 * q + 2] = e.z; whz[4 * q + 3] = e.w;
        whn[4 * q + 0] = f.x; whn[4 * q + 1] = f.y; whn[4 * q + 2] = f.z; whn[4 * q + 3] = f.w;
    }
    float bir = bih[j], biz = bih[64 + j], bin = bih[128 + j];
    float bhr = bhh[j], bhz = bhh[64 + j], bhn = bhh[128 + j];
    float h = 0.f;
    const float* xb = IN + (size_t)n * TT * HH;
    float* yb = yout ? (yout + (size_t)n * TT * HH) : (float*)0;
#pragma unroll 1
    for (int t = 0; t < TT; ++t) {
        float xv = xb[t * HH + j];
        float arx = bir, azx = biz, anx = bin;
        float arh = bhr, azh = bhz, anh = bhn;
#pragma unroll
        for (int k = 0; k < 64; ++k) {
            float sx = __int_as_float(__builtin_amdgcn_readlane(__float_as_int(xv), k));
            float sh = __int_as_float(__builtin_amdgcn_readlane(__float_as_int(h), k));
            arx += sx * wxr[k]; azx += sx * wxz[k]; anx += sx * wxn[k];
            arh += sh * whr[k]; azh += sh * whz[k]; anh += sh * whn[k];
        }
        float r = fsigmoid(arx + arh);
        float z = fsigmoid(azx + azh);
        float nn2 = tanhf(anx + r * anh);
        h = (1.f - z) * nn2 + z * h;
        if (yb) yb[t * HH + j] = h;
    }
    hout[(size_t)n * HH + j] = h;
}

// ---------------- head: BN + relu + linear + log_softmax ----------------
__global__ __launch_bounds__(256) void k_head(const float* __restrict__ Hf,
                                              const float* __restrict__ g, const float* __restrict__ b,
                                              const float* __restrict__ m, const float* __restrict__ v,
                                              const float* __restrict__ W, const float* __restrict__ wb,
                                              float* __restrict__ out) {
    __shared__ float hb[4][HH];
    __shared__ float lg[4][CC];
    int tid = threadIdx.x;
    int n0 = blockIdx.x * 4;
    int wv = tid >> 6, lane = tid & 63;
    int n = n0 + wv;
    float x = Hf[(size_t)n * HH + lane];
    x = (x - m[lane]) * rsqrtf(v[lane] + EPSBN) * g[lane] + b[lane];
    hb[wv][lane] = fmaxf(x, 0.f);
    __syncthreads();
    if (tid < 4 * CC) {
        int nn = tid / CC, c = tid % CC;
        float acc = wb[c];
        for (int f = 0; f < HH; ++f) acc += hb[nn][f] * W[c * HH + f];
        lg[nn][c] = acc;
    }
    __syncthreads();
    if (tid < 4 * CC) {
        int nn = tid / CC, c = tid % CC;
        float mx = -1e30f;
#pragma unroll
        for (int i = 0; i < CC; ++i) mx = fmaxf(mx, lg[nn][i]);
        float s = 0.f;
#pragma unroll
        for (int i = 0; i < CC; ++i) s += __expf(lg[nn][i] - mx);
        out[(size_t)(n0 + nn) * CC + c] = lg[nn][c] - mx - __logf(s);
    }
}

// ---------------- launch ----------------
extern "C" void kernel_launch(void* const* d_in, const int* in_sizes, int n_in,
                              void* d_out, int out_size, void* d_ws, size_t ws_size,
                              hipStream_t stream) {
    const float* x_seq     = (const float*)d_in[0];
    const int*   edge_idx  = (const int*)d_in[1];
    const float* edge_w    = (const float*)d_in[2];
    const float* causal_w  = (const float*)d_in[3];
    const float* lin_in_w  = (const float*)d_in[4];
    const float* lin_in_b  = (const float*)d_in[5];
    const float* fusion_w  = (const float*)d_in[6];
    const float* fusion_b  = (const float*)d_in[7];
    const float* gcn_w0    = (const float*)d_in[8];
    const float* gcn_b0    = (const float*)d_in[9];
    const float* gcn_w1    = (const float*)d_in[10];
    const float* gcn_b1    = (const float*)d_in[11];
    const float* bn0_g = (const float*)d_in[12], *bn0_b = (const float*)d_in[13];
    const float* bn0_m = (const float*)d_in[14], *bn0_v = (const float*)d_in[15];
    const float* bn1_g = (const float*)d_in[16], *bn1_b = (const float*)d_in[17];
    const float* bn1_m = (const float*)d_in[18], *bn1_v = (const float*)d_in[19];
    const float* wih0 = (const float*)d_in[20], *whh0 = (const float*)d_in[21];
    const float* bih0 = (const float*)d_in[22], *bhh0 = (const float*)d_in[23];
    const float* wih1 = (const float*)d_in[24], *whh1 = (const float*)d_in[25];
    const float* bih1 = (const float*)d_in[26], *bhh1 = (const float*)d_in[27];
    const float* bno_g = (const float*)d_in[28], *bno_b = (const float*)d_in[29];
    const float* bno_m = (const float*)d_in[30], *bno_v = (const float*)d_in[31];
    const float* lout_w = (const float*)d_in[32], *lout_b = (const float*)d_in[33];
    float* out = (float*)d_out;

    float* wsf = (float*)d_ws;
    unsigned short* WCH = (unsigned short*)(wsf + OFF_WC);
    float* XA  = wsf + OFF_XA;
    float* XB  = wsf + OFF_XB;
    float* XC  = wsf + OFF_XC;
    unsigned short* XAT = (unsigned short*)(wsf + OFF_XC);
    float* DEG = wsf + OFF_DEG;
    int* CNT   = (int*)(wsf + OFF_CNT);
    int* CUR   = (int*)(wsf + OFF_CUR);
    int* OFFP  = (int*)(wsf + OFF_OFF);
    int* CSRS  = (int*)(wsf + OFF_CSRS);
    float* CSRN = wsf + OFF_CSRN;
    float* HST  = wsf + OFF_HST;

    // CSR + degree build
    k_zero<<<8, 256, 0, stream>>>(CNT, CUR, DEG);
    k_count<<<(ETOT + 255) / 256, 256, 0, stream>>>(edge_idx, edge_w, CNT, DEG);
    k_scan<<<1, 1024, 0, stream>>>(CNT, OFFP);
    k_fill<<<(ETOT + 255) / 256, 256, 0, stream>>>(edge_idx, edge_w, DEG, OFFP, CUR, CSRS, CSRN);

    hipMemsetAsync(WCH, 0, (size_t)2048 * 2048 * 2, stream);
    k_softmax<<<NN, 256, 0, stream>>>(causal_w, WCH);
    // lin_in -> XA [N,T,H] fp32
    k_lin2<<<NN, 256, 0, stream>>>(x_seq, lin_in_w, lin_in_b, XA);
    // transpose+cast: XA -> XAh_t bf16 [4096][2048]
    dim3 tg(THL / 64, 2048 / 64);
    k_tr<<<tg, 256, 0, stream>>>(XA, XAT);
    // x_agg = WCh @ X (MFMA bf16) -> XB fp32
    dim3 gg(THL / 128, 2048 / 128);
    k_gemm_bf<<<gg, 256, 0, stream>>>(WCH, XAT, XB);
    // fusion -> XC
    k_fus2<<<NN, 256, 0, stream>>>(XA, XB, fusion_w, fusion_b, XC);
    // GCN layer 0: XC -> XB (xw) -> XA (agg+bn+relu)
    k_xw2<<<NN, 256, 0, stream>>>(XC, gcn_w0, XB);
    dim3 ag(NN, 4);
    k_agg<<<ag, 256, 0, stream>>>(XB, OFFP, CSRS, CSRN, gcn_b0, bn0_g, bn0_b, bn0_m, bn0_v, XA);
    // GCN layer 1: XA -> XB -> XC
    k_xw2<<<NN, 256, 0, stream>>>(XA, gcn_w1, XB);
    k_agg<<<ag, 256, 0, stream>>>(XB, OFFP, CSRS, CSRN, gcn_b1, bn1_g, bn1_b, bn1_m, bn1_v, XC);

    // fused GRU: layer 0 (XC -> H0 in XA), layer 1 (XA -> final h in HST)
    k_gruL<<<NN, 64, 0, stream>>>(XC, wih0, whh0, bih0, bhh0, HST, XA);
    k_gruL<<<NN, 64, 0, stream>>>(XA, wih1, whh1, bih1, bhh1, HST, (float*)nullptr);

    // head
    k_head<<<NN / 4, 256, 0, stream>>>(HST, bno_g, bno_b, bno_m, bno_v, lout_w, lout_b, out);
}

// Round 13
// 784.626 us; speedup vs baseline: 1.3217x; 1.3217x over previous
//
#include <hip/hip_runtime.h>
#include <hip/hip_bf16.h>
#include <math.h>

#define TT 64
#define NN 2000
#define FIN 32
#define HH 64
#define CC 10
#define EE 32000
#define ETOT 34000   // E + N self loops
#define THL 4096     // T*H
#define EPSBN 1e-5f
#define CHT 16       // GRU time-chunk

// ---------------- workspace layout (float offsets) ----------------
#define OFF_WC   0u          // WCh bf16 [2048][2048]
#define OFF_XA   4000000u    // 8,192,000  [N,T,H] fp32
#define OFF_XB   12192000u   // 8,192,000  (x_agg bf16 C; then xw scratch / GI buffer)
#define OFF_XC   20384000u   // 8,192,000  (first: XAh_t bf16 [4096][2048]; then fusion out fp32)
#define OFF_DEG  28576000u   // 2048
#define OFF_H1   28578048u   // 128,000 (unused)
#define OFF_CNT  28706048u   // int 2048
#define OFF_CUR  28708096u   // int 2048
#define OFF_OFF  28710144u   // int 2064
#define OFF_CSRS 28712208u   // int 34016
#define OFF_CSRN 28746224u   // float 34016
#define OFF_HST  28780240u   // float 128,000  (GRU h-state)

typedef __attribute__((ext_vector_type(8))) short short8v;
typedef __attribute__((ext_vector_type(4))) float f32x4;

__device__ __forceinline__ float fsigmoid(float x) { return 1.f / (1.f + __expf(-x)); }
__device__ __forceinline__ unsigned short f2bf(float f) {
    __hip_bfloat16 h = __float2bfloat16(f);
    return *reinterpret_cast<unsigned short*>(&h);
}
__device__ __forceinline__ float bf2f(unsigned short u) {
    unsigned int x = ((unsigned int)u) << 16;
    return __int_as_float(x);
}

// ---------------- CSR build ----------------
__global__ void k_zero(int* cnt, int* cur, float* deg) {
    int i = blockIdx.x * 256 + threadIdx.x;
    if (i < 2048) { cnt[i] = 0; cur[i] = 0; deg[i] = 0.f; }
}

__global__ void k_count(const int* __restrict__ ei, const float* __restrict__ ew,
                        int* cnt, float* deg) {
    int e = blockIdx.x * 256 + threadIdx.x;
    if (e < ETOT) {
        int dst; float w;
        if (e < EE) { dst = ei[EE + e]; w = ew[e]; }
        else        { dst = e - EE;     w = 1.f; }
        atomicAdd(&cnt[dst], 1);
        atomicAdd(&deg[dst], w);
    }
}

__global__ __launch_bounds__(1024) void k_scan(const int* __restrict__ cnt, int* off) {
    __shared__ int s[2048];
    int tid = threadIdx.x;
    s[tid]        = (tid        < NN) ? cnt[tid]        : 0;
    s[tid + 1024] = (tid + 1024 < NN) ? cnt[tid + 1024] : 0;
    __syncthreads();
    for (int d = 1; d < 2048; d <<= 1) {
        int idx = (tid + 1) * (d << 1) - 1;
        if (idx < 2048) s[idx] += s[idx - d];
        __syncthreads();
    }
    if (tid == 0) s[2047] = 0;
    __syncthreads();
    for (int d = 1024; d >= 1; d >>= 1) {
        int idx = (tid + 1) * (d << 1) - 1;
        if (idx < 2048) { int t = s[idx - d]; s[idx - d] = s[idx]; s[idx] += t; }
        __syncthreads();
    }
    off[tid] = s[tid];
    off[tid + 1024] = s[tid + 1024];
}

__global__ void k_fill(const int* __restrict__ ei, const float* __restrict__ ew,
                       const float* __restrict__ deg, const int* __restrict__ off,
                       int* cur, int* csr_src, float* csr_nrm) {
    int e = blockIdx.x * 256 + threadIdx.x;
    if (e < ETOT) {
        int src, dst; float w;
        if (e < EE) { src = ei[e]; dst = ei[EE + e]; w = ew[e]; }
        else        { src = dst = e - EE;            w = 1.f; }
        float ds = rsqrtf(fmaxf(deg[src], 1e-12f));
        float dd = rsqrtf(fmaxf(deg[dst], 1e-12f));
        int pos = off[dst] + atomicAdd(&cur[dst], 1);
        csr_src[pos] = src;
        csr_nrm[pos] = ds * w * dd;
    }
}

// ---------------- softmax over causal_weight rows -> bf16 WCh [2048 stride] ----------------
__global__ __launch_bounds__(256) void k_softmax(const float* __restrict__ CW,
                                                 unsigned short* __restrict__ WCH) {
    __shared__ float row[NN];
    __shared__ float red[256];
    int r = blockIdx.x, tid = threadIdx.x;
    const float* in = CW + (size_t)r * NN;
    float mx = -1e30f;
    for (int i = tid; i < NN; i += 256) { float v = in[i]; row[i] = v; mx = fmaxf(mx, v); }
    red[tid] = mx; __syncthreads();
    for (int s = 128; s > 0; s >>= 1) {
        if (tid < s) red[tid] = fmaxf(red[tid], red[tid + s]);
        __syncthreads();
    }
    mx = red[0]; __syncthreads();
    float sm = 0.f;
    for (int i = tid; i < NN; i += 256) { float e = __expf(row[i] - mx); row[i] = e; sm += e; }
    red[tid] = sm; __syncthreads();
    for (int s = 128; s > 0; s >>= 1) {
        if (tid < s) red[tid] += red[tid + s];
        __syncthreads();
    }
    float inv = 1.f / red[0];
    unsigned short* out = WCH + (size_t)r * 2048;
    for (int i = tid; i < 2048; i += 256)
        out[i] = (i < NN) ? f2bf(row[i] * inv) : (unsigned short)0;
}

// ---------------- lin_in as tiled GEMM: rows=(n,t), K=32, 64 cols ----------------
__global__ __launch_bounds__(256) void k_lin2(const float* __restrict__ XS,
                                              const float* __restrict__ W,
                                              const float* __restrict__ b,
                                              float* __restrict__ OUT) {
    __shared__ float Wt[FIN][68];   // [k][o]
    __shared__ float As[FIN][68];   // [k][row]
    int tid = threadIdx.x;
    int n = blockIdx.x;
    for (int i = tid; i < HH * FIN; i += 256) { int o = i >> 5, k = i & 31; Wt[k][o] = W[i]; }
    int row = tid >> 2, kq = tid & 3;   // row = t
    {
        const float4* src = (const float4*)(XS + ((size_t)row * NN + n) * FIN + kq * 8);
        float4 v0 = src[0], v1 = src[1];
        As[kq * 8 + 0][row] = v0.x; As[kq * 8 + 1][row] = v0.y;
        As[kq * 8 + 2][row] = v0.z; As[kq * 8 + 3][row] = v0.w;
        As[kq * 8 + 4][row] = v1.x; As[kq * 8 + 5][row] = v1.y;
        As[kq * 8 + 6][row] = v1.z; As[kq * 8 + 7][row] = v1.w;
    }
    __syncthreads();
    int tx = tid & 15, ty = tid >> 4;
    float acc[4][4] = {};
#pragma unroll
    for (int k = 0; k < FIN; ++k) {
        float4 av = *(const float4*)&As[k][ty * 4];
        float4 wv = *(const float4*)&Wt[k][tx * 4];
        acc[0][0] += av.x * wv.x; acc[0][1] += av.x * wv.y; acc[0][2] += av.x * wv.z; acc[0][3] += av.x * wv.w;
        acc[1][0] += av.y * wv.x; acc[1][1] += av.y * wv.y; acc[1][2] += av.y * wv.z; acc[1][3] += av.y * wv.w;
        acc[2][0] += av.z * wv.x; acc[2][1] += av.z * wv.y; acc[2][2] += av.z * wv.z; acc[2][3] += av.z * wv.w;
        acc[3][0] += av.w * wv.x; acc[3][1] += av.w * wv.y; acc[3][2] += av.w * wv.z; acc[3][3] += av.w * wv.w;
    }
    float4 bv = *(const float4*)(b + tx * 4);
#pragma unroll
    for (int ii = 0; ii < 4; ++ii) {
        float4 o;
        o.x = fmaxf(acc[ii][0] + bv.x, 0.f);
        o.y = fmaxf(acc[ii][1] + bv.y, 0.f);
        o.z = fmaxf(acc[ii][2] + bv.z, 0.f);
        o.w = fmaxf(acc[ii][3] + bv.w, 0.f);
        *(float4*)(OUT + ((size_t)n * TT + ty * 4 + ii) * HH + tx * 4) = o;
    }
}

// ---------------- transpose + bf16 cast ----------------
__global__ __launch_bounds__(256) void k_tr(const float* __restrict__ X,
                                            unsigned short* __restrict__ XT) {
    __shared__ unsigned short tile[64][65];
    int cb = blockIdx.x * 64;
    int kb = blockIdx.y * 64;
    int tid = threadIdx.x;
    int r = tid >> 2, cq = tid & 3;
    const float4* src = (const float4*)(X + (size_t)(kb + r) * THL + cb + cq * 16);
#pragma unroll
    for (int j = 0; j < 4; ++j) {
        float4 v = src[j];
        tile[cq * 16 + j * 4 + 0][r] = f2bf(v.x);
        tile[cq * 16 + j * 4 + 1][r] = f2bf(v.y);
        tile[cq * 16 + j * 4 + 2][r] = f2bf(v.z);
        tile[cq * 16 + j * 4 + 3][r] = f2bf(v.w);
    }
    __syncthreads();
    int cl = tid >> 2, kq = tid & 3;
    unsigned short tmp[16];
#pragma unroll
    for (int j = 0; j < 16; ++j) tmp[j] = tile[cl][kq * 16 + j];
    unsigned short* dst = XT + (size_t)(cb + cl) * 2048 + kb + kq * 16;
    *(uint4*)dst = *(uint4*)tmp;
    *(uint4*)(dst + 8) = *(uint4*)(tmp + 8);
}

// ---------------- bf16 MFMA GEMM: C(bf16)[2000,4096] = WCh @ X (via XAh_t) ----------------
// R13: C output in bf16 (halves logical C bytes 32->16MB; write-amplification
// mechanism unexplained after R6-R11 — this halves whatever it amplifies).
__global__ __launch_bounds__(256, 1) void k_gemm_bf(const unsigned short* __restrict__ A,
                                                    const unsigned short* __restrict__ B,
                                                    unsigned short* __restrict__ CH) {
    __shared__ unsigned short As[128][72];
    __shared__ unsigned short Bs[128][72];
    int tid = threadIdx.x;
    int mb = blockIdx.y * 128, nb = blockIdx.x * 128;
    int w = tid >> 6, lane = tid & 63;
    int wr = w >> 1, wc = w & 1;
    int l15 = lane & 15, l4 = lane >> 4;
    f32x4 acc[4][4] = {};
    int arow = tid >> 3, acol = tid & 7;   // 8 threads per row, 16B each
    const uint4* ga = (const uint4*)(A + (size_t)(mb + arow) * 2048 + acol * 8);
    const uint4* gb = (const uint4*)(B + (size_t)(nb + arow) * 2048 + acol * 8);
    uint4 va[4], vb[4];
#pragma unroll
    for (int i = 0; i < 4; ++i) { va[i] = ga[(size_t)i * 8192]; vb[i] = gb[(size_t)i * 8192]; }
    ga += 8; gb += 8;
    for (int kt = 0; kt < 32; ++kt) {
        __syncthreads();
#pragma unroll
        for (int i = 0; i < 4; ++i) {
            *(uint4*)&As[arow + i * 32][acol * 8] = va[i];
            *(uint4*)&Bs[arow + i * 32][acol * 8] = vb[i];
        }
        __syncthreads();
        if (kt < 31) {
#pragma unroll
            for (int i = 0; i < 4; ++i) { va[i] = ga[(size_t)i * 8192]; vb[i] = gb[(size_t)i * 8192]; }
            ga += 8; gb += 8;
        }
#pragma unroll
        for (int kk = 0; kk < 2; ++kk) {
            short8v af[4], bfr[4];
#pragma unroll
            for (int f = 0; f < 4; ++f) {
                af[f]  = *(const short8v*)&As[wr * 64 + f * 16 + l15][kk * 32 + l4 * 8];
                bfr[f] = *(const short8v*)&Bs[wc * 64 + f * 16 + l15][kk * 32 + l4 * 8];
            }
#pragma unroll
            for (int fm = 0; fm < 4; ++fm)
#pragma unroll
                for (int fn = 0; fn < 4; ++fn)
                    acc[fm][fn] = __builtin_amdgcn_mfma_f32_16x16x32_bf16(af[fm], bfr[fn], acc[fm][fn], 0, 0, 0);
        }
    }
    // ---- epilogue: bf16 LDS staging -> full-row (128B) stores ----
    unsigned short* epi = (unsigned short*)(&As[0][0]) + (size_t)w * (16 * 72);
    int erow8 = lane >> 3;      // 0..7
    int ecol8 = lane & 7;       // 8 lanes x 8 bf16 (16B) = full 128B row
#pragma unroll
    for (int fm = 0; fm < 4; ++fm) {
        __syncthreads();
#pragma unroll
        for (int fn = 0; fn < 4; ++fn)
#pragma unroll
            for (int rr = 0; rr < 4; ++rr)
                epi[(l4 * 4 + rr) * 72 + fn * 16 + l15] = f2bf(acc[fm][fn][rr]);
        __syncthreads();
#pragma unroll
        for (int rh = 0; rh < 2; ++rh) {
            int lrow = rh * 8 + erow8;
            int grow = mb + wr * 64 + fm * 16 + lrow;
            if (grow < NN) {
                *(uint4*)(CH + (size_t)grow * THL + nb + wc * 64 + ecol8 * 8)
                    = *(const uint4*)&epi[lrow * 72 + ecol8 * 8];
            }
        }
    }
}

// ---------------- fusion as tiled GEMM: K=128 (X fp32 + XAgg bf16), 64 cols ----------------
__global__ __launch_bounds__(256) void k_fus2(const float* __restrict__ X,
                                              const unsigned short* __restrict__ XAH,
                                              const float* __restrict__ W,
                                              const float* __restrict__ b,
                                              float* __restrict__ OUT) {
    __shared__ float Wt[2 * HH][68];  // [k][o], k = 0..127
    __shared__ float As[HH][68];      // [k][row]
    int tid = threadIdx.x;
    size_t r0 = (size_t)blockIdx.x * 64;
    for (int i = tid; i < HH * 2 * HH; i += 256) { int o = i >> 7, k = i & 127; Wt[k][o] = W[i]; }
    int row = tid >> 2, kq = tid & 3;
    int tx = tid & 15, ty = tid >> 4;
    float acc[4][4] = {};
    // ---- phase 0: X (fp32) ----
    __syncthreads();
    {
        const float4* src = (const float4*)(X + (r0 + row) * HH + kq * 16);
#pragma unroll
        for (int j = 0; j < 4; ++j) {
            float4 v = src[j];
            As[kq * 16 + j * 4 + 0][row] = v.x;
            As[kq * 16 + j * 4 + 1][row] = v.y;
            As[kq * 16 + j * 4 + 2][row] = v.z;
            As[kq * 16 + j * 4 + 3][row] = v.w;
        }
    }
    __syncthreads();
#pragma unroll
    for (int k = 0; k < HH; ++k) {
        float4 av = *(const float4*)&As[k][ty * 4];
        float4 wv = *(const float4*)&Wt[k][tx * 4];
        acc[0][0] += av.x * wv.x; acc[0][1] += av.x * wv.y; acc[0][2] += av.x * wv.z; acc[0][3] += av.x * wv.w;
        acc[1][0] += av.y * wv.x; acc[1][1] += av.y * wv.y; acc[1][2] += av.y * wv.z; acc[1][3] += av.y * wv.w;
        acc[2][0] += av.z * wv.x; acc[2][1] += av.z * wv.y; acc[2][2] += av.z * wv.z; acc[2][3] += av.z * wv.w;
        acc[3][0] += av.w * wv.x; acc[3][1] += av.w * wv.y; acc[3][2] += av.w * wv.z; acc[3][3] += av.w * wv.w;
    }
    // ---- phase 1: XAgg (bf16) ----
    __syncthreads();
    {
        const uint4* s = (const uint4*)(XAH + (r0 + row) * HH + kq * 16);
        uint4 u0 = s[0], u1 = s[1];   // 16 bf16
        unsigned short us[16];
        *(uint4*)us = u0; *(uint4*)(us + 8) = u1;
#pragma unroll
        for (int j = 0; j < 16; ++j)
            As[kq * 16 + j][row] = bf2f(us[j]);
    }
    __syncthreads();
#pragma unroll
    for (int k = 0; k < HH; ++k) {
        float4 av = *(const float4*)&As[k][ty * 4];
        float4 wv = *(const float4*)&Wt[HH + k][tx * 4];
        acc[0][0] += av.x * wv.x; acc[0][1] += av.x * wv.y; acc[0][2] += av.x * wv.z; acc[0][3] += av.x * wv.w;
        acc[1][0] += av.y * wv.x; acc[1][1] += av.y * wv.y; acc[1][2] += av.y * wv.z; acc[1][3] += av.y * wv.w;
        acc[2][0] += av.z * wv.x; acc[2][1] += av.z * wv.y; acc[2][2] += av.z * wv.z; acc[2][3] += av.z * wv.w;
        acc[3][0] += av.w * wv.x; acc[3][1] += av.w * wv.y; acc[3][2] += av.w * wv.z; acc[3][3] += av.w * wv.w;
    }
    float4 bv = *(const float4*)(b + tx * 4);
#pragma unroll
    for (int ii = 0; ii < 4; ++ii) {
        float4 o;
        o.x = fmaxf(acc[ii][0] + bv.x, 0.f);
        o.y = fmaxf(acc[ii][1] + bv.y, 0.f);
        o.z = fmaxf(acc[ii][2] + bv.z, 0.f);
        o.w = fmaxf(acc[ii][3] + bv.w, 0.f);
        *(float4*)(OUT + (r0 + ty * 4 + ii) * HH + tx * 4) = o;
    }
}

// ---------------- GCN xw as tiled GEMM: K=64, 64 cols, no bias ----------------
__global__ __launch_bounds__(256) void k_xw2(const float* __restrict__ IN,
                                             const float* __restrict__ W,
                                             float* __restrict__ OUT) {
    __shared__ float Wt[HH][68];
    __shared__ float As[HH][68];
    int tid = threadIdx.x;
    size_t r0 = (size_t)blockIdx.x * 64;
    for (int i = tid; i < HH * HH; i += 256) { int o = i >> 6, k = i & 63; Wt[k][o] = W[i]; }
    int row = tid >> 2, kq = tid & 3;
    {
        const float4* src = (const float4*)(IN + (r0 + row) * HH + kq * 16);
#pragma unroll
        for (int j = 0; j < 4; ++j) {
            float4 v = src[j];
            As[kq * 16 + j * 4 + 0][row] = v.x;
            As[kq * 16 + j * 4 + 1][row] = v.y;
            As[kq * 16 + j * 4 + 2][row] = v.z;
            As[kq * 16 + j * 4 + 3][row] = v.w;
        }
    }
    __syncthreads();
    int tx = tid & 15, ty = tid >> 4;
    float acc[4][4] = {};
#pragma unroll
    for (int k = 0; k < HH; ++k) {
        float4 av = *(const float4*)&As[k][ty * 4];
        float4 wv = *(const float4*)&Wt[k][tx * 4];
        acc[0][0] += av.x * wv.x; acc[0][1] += av.x * wv.y; acc[0][2] += av.x * wv.z; acc[0][3] += av.x * wv.w;
        acc[1][0] += av.y * wv.x; acc[1][1] += av.y * wv.y; acc[1][2] += av.y * wv.z; acc[1][3] += av.y * wv.w;
        acc[2][0] += av.z * wv.x; acc[2][1] += av.z * wv.y; acc[2][2] += av.z * wv.z; acc[2][3] += av.z * wv.w;
        acc[3][0] += av.w * wv.x; acc[3][1] += av.w * wv.y; acc[3][2] += av.w * wv.z; acc[3][3] += av.w * wv.w;
    }
#pragma unroll
    for (int ii = 0; ii < 4; ++ii) {
        float4 o = make_float4(acc[ii][0], acc[ii][1], acc[ii][2], acc[ii][3]);
        *(float4*)(OUT + (r0 + ty * 4 + ii) * HH + tx * 4) = o;
    }
}

// ---------------- GCN aggregate (CSR) + bias + BN + relu, column-chunked ----------------
__global__ __launch_bounds__(256) void k_agg(const float* __restrict__ XW,
                                             const int* __restrict__ off,
                                             const int* __restrict__ csr_src,
                                             const float* __restrict__ csr_nrm,
                                             const float* __restrict__ bias,
                                             const float* __restrict__ g,
                                             const float* __restrict__ bb,
                                             const float* __restrict__ m,
                                             const float* __restrict__ v,
                                             float* __restrict__ OUT) {
    int dst = blockIdx.x, ch = blockIdx.y, tid = threadIdx.x;
    int base = ch * 1024 + tid * 4;
    float4 acc = make_float4(0.f, 0.f, 0.f, 0.f);
    int beg = off[dst], end = off[dst + 1];
    for (int e = beg; e < end; ++e) {
        int src = csr_src[e];
        float w = csr_nrm[e];
        float4 x = *(const float4*)(XW + (size_t)src * THL + base);
        acc.x += w * x.x; acc.y += w * x.y; acc.z += w * x.z; acc.w += w * x.w;
    }
    int h0 = base & 63;
    float4 bs = *(const float4*)(bias + h0);
    float4 gv = *(const float4*)(g + h0);
    float4 vv = *(const float4*)(v + h0);
    float4 mv = *(const float4*)(m + h0);
    float4 bv = *(const float4*)(bb + h0);
    float4 o;
    o.x = fmaxf((acc.x + bs.x - mv.x) * rsqrtf(vv.x + EPSBN) * gv.x + bv.x, 0.f);
    o.y = fmaxf((acc.y + bs.y - mv.y) * rsqrtf(vv.y + EPSBN) * gv.y + bv.y, 0.f);
    o.z = fmaxf((acc.z + bs.z - mv.z) * rsqrtf(vv.z + EPSBN) * gv.z + bv.z, 0.f);
    o.w = fmaxf((acc.w + bs.w - mv.w) * rsqrtf(vv.w + EPSBN) * gv.w + bv.w, 0.f);
    *(float4*)(OUT + (size_t)dst * THL + base) = o;
}

// ---------------- GRU gi as tiled GEMM: rows=(n,tc) chunk, K=64, 192 cols in 3 slabs ----------------
__global__ __launch_bounds__(256) void k_gi2(const float* __restrict__ IN,
                                             const float* __restrict__ wih,
                                             const float* __restrict__ bih,
                                             float* __restrict__ GI, int t0) {
    __shared__ float Wt[HH][68];
    __shared__ float As[HH][68];
    int tid = threadIdx.x;
    int r0 = blockIdx.x * 64;          // row tile (r = n*CHT + tc)
    int cb = blockIdx.y * 64;          // col slab base (0/64/128)
    for (int i = tid; i < 64 * HH; i += 256) {
        int o = i >> 6, k = i & 63;
        Wt[k][o] = wih[(size_t)(cb + o) * HH + k];
    }
    int row = tid >> 2, kq = tid & 3;
    {
        int rr = r0 + row;
        int n = rr >> 4, tc = rr & 15;
        const float4* src = (const float4*)(IN + ((size_t)n * TT + t0 + tc) * HH + kq * 16);
#pragma unroll
        for (int j = 0; j < 4; ++j) {
            float4 v = src[j];
            As[kq * 16 + j * 4 + 0][row] = v.x;
            As[kq * 16 + j * 4 + 1][row] = v.y;
            As[kq * 16 + j * 4 + 2][row] = v.z;
            As[kq * 16 + j * 4 + 3][row] = v.w;
        }
    }
    __syncthreads();
    int tx = tid & 15, ty = tid >> 4;
    float acc[4][4] = {};
#pragma unroll
    for (int k = 0; k < HH; ++k) {
        float4 av = *(const float4*)&As[k][ty * 4];
        float4 wv = *(const float4*)&Wt[k][tx * 4];
        acc[0][0] += av.x * wv.x; acc[0][1] += av.x * wv.y; acc[0][2] += av.x * wv.z; acc[0][3] += av.x * wv.w;
        acc[1][0] += av.y * wv.x; acc[1][1] += av.y * wv.y; acc[1][2] += av.y * wv.z; acc[1][3] += av.y * wv.w;
        acc[2][0] += av.z * wv.x; acc[2][1] += av.z * wv.y; acc[2][2] += av.z * wv.z; acc[2][3] += av.z * wv.w;
        acc[3][0] += av.w * wv.x; acc[3][1] += av.w * wv.y; acc[3][2] += av.w * wv.z; acc[3][3] += av.w * wv.w;
    }
    float4 bv = *(const float4*)(bih + cb + tx * 4);
#pragma unroll
    for (int ii = 0; ii < 4; ++ii) {
        float4 o;
        o.x = acc[ii][0] + bv.x;
        o.y = acc[ii][1] + bv.y;
        o.z = acc[ii][2] + bv.z;
        o.w = acc[ii][3] + bv.w;
        *(float4*)(GI + (size_t)(r0 + ty * 4 + ii) * 192 + cb + tx * 4) = o;
    }
}

// ---------------- GRU part B: recurrence, one wave per node ----------------
__global__ __launch_bounds__(256, 2) void k_rec(const float* __restrict__ GI,
                                                const float* __restrict__ whh,
                                                const float* __restrict__ bhh,
                                                float* __restrict__ hstate,
                                                float* __restrict__ yout,
                                                int t0, int first) {
    int tid = threadIdx.x;
    int wv = tid >> 6, j = tid & 63;
    int n = blockIdx.x * 4 + wv;
    float wr[64], wz[64], wn[64];
    const float4* w4 = (const float4*)whh;
#pragma unroll
    for (int q = 0; q < 16; ++q) {
        float4 a = w4[(size_t)j * 16 + q];
        float4 b = w4[(size_t)(64 + j) * 16 + q];
        float4 c = w4[(size_t)(128 + j) * 16 + q];
        wr[4 * q + 0] = a.x; wr[4 * q + 1] = a.y; wr[4 * q + 2] = a.z; wr[4 * q + 3] = a.w;
        wz[4 * q + 0] = b.x; wz[4 * q + 1] = b.y; wz[4 * q + 2] = b.z; wz[4 * q + 3] = b.w;
        wn[4 * q + 0] = c.x; wn[4 * q + 1] = c.y; wn[4 * q + 2] = c.z; wn[4 * q + 3] = c.w;
    }
    float bhr = bhh[j], bhz = bhh[64 + j], bhn = bhh[128 + j];
    float h = first ? 0.f : hstate[(size_t)n * HH + j];
    const float* gp = GI + (size_t)n * (CHT * 192);
    for (int tc = 0; tc < CHT; ++tc) {
        float gr = gp[tc * 192 + j];
        float gz = gp[tc * 192 + 64 + j];
        float gn = gp[tc * 192 + 128 + j];
        float ar = bhr, az = bhz, an = bhn;
#pragma unroll
        for (int k = 0; k < 64; ++k) {
            float s = __int_as_float(__builtin_amdgcn_readlane(__float_as_int(h), k));
            ar += s * wr[k]; az += s * wz[k]; an += s * wn[k];
        }
        float r = fsigmoid(gr + ar);
        float z = fsigmoid(gz + az);
        float nn2 = tanhf(gn + r * an);
        h = (1.f - z) * nn2 + z * h;
        if (yout) yout[((size_t)n * TT + (t0 + tc)) * HH + j] = h;
    }
    hstate[(size_t)n * HH + j] = h;
}

// ---------------- head: BN + relu + linear + log_softmax ----------------
__global__ __launch_bounds__(256) void k_head(const float* __restrict__ Hf,
                                              const float* __restrict__ g, const float* __restrict__ b,
                                              const float* __restrict__ m, const float* __restrict__ v,
                                              const float* __restrict__ W, const float* __restrict__ wb,
                                              float* __restrict__ out) {
    __shared__ float hb[4][HH];
    __shared__ float lg[4][CC];
    int tid = threadIdx.x;
    int n0 = blockIdx.x * 4;
    int wv = tid >> 6, lane = tid & 63;
    int n = n0 + wv;
    float x = Hf[(size_t)n * HH + lane];
    x = (x - m[lane]) * rsqrtf(v[lane] + EPSBN) * g[lane] + b[lane];
    hb[wv][lane] = fmaxf(x, 0.f);
    __syncthreads();
    if (tid < 4 * CC) {
        int nn = tid / CC, c = tid % CC;
        float acc = wb[c];
        for (int f = 0; f < HH; ++f) acc += hb[nn][f] * W[c * HH + f];
        lg[nn][c] = acc;
    }
    __syncthreads();
    if (tid < 4 * CC) {
        int nn = tid / CC, c = tid % CC;
        float mx = -1e30f;
#pragma unroll
        for (int i = 0; i < CC; ++i) mx = fmaxf(mx, lg[nn][i]);
        float s = 0.f;
#pragma unroll
        for (int i = 0; i < CC; ++i) s += __expf(lg[nn][i] - mx);
        out[(size_t)(n0 + nn) * CC + c] = lg[nn][c] - mx - __logf(s);
    }
}

// ---------------- launch ----------------
extern "C" void kernel_launch(void* const* d_in, const int* in_sizes, int n_in,
                              void* d_out, int out_size, void* d_ws, size_t ws_size,
                              hipStream_t stream) {
    const float* x_seq     = (const float*)d_in[0];
    const int*   edge_idx  = (const int*)d_in[1];
    const float* edge_w    = (const float*)d_in[2];
    const float* causal_w  = (const float*)d_in[3];
    const float* lin_in_w  = (const float*)d_in[4];
    const float* lin_in_b  = (const float*)d_in[5];
    const float* fusion_w  = (const float*)d_in[6];
    const float* fusion_b  = (const float*)d_in[7];
    const float* gcn_w0    = (const float*)d_in[8];
    const float* gcn_b0    = (const float*)d_in[9];
    const float* gcn_w1    = (const float*)d_in[10];
    const float* gcn_b1    = (const float*)d_in[11];
    const float* bn0_g = (const float*)d_in[12], *bn0_b = (const float*)d_in[13];
    const float* bn0_m = (const float*)d_in[14], *bn0_v = (const float*)d_in[15];
    const float* bn1_g = (const float*)d_in[16], *bn1_b = (const float*)d_in[17];
    const float* bn1_m = (const float*)d_in[18], *bn1_v = (const float*)d_in[19];
    const float* wih0 = (const float*)d_in[20], *whh0 = (const float*)d_in[21];
    const float* bih0 = (const float*)d_in[22], *bhh0 = (const float*)d_in[23];
    const float* wih1 = (const float*)d_in[24], *whh1 = (const float*)d_in[25];
    const float* bih1 = (const float*)d_in[26], *bhh1 = (const float*)d_in[27];
    const float* bno_g = (const float*)d_in[28], *bno_b = (const float*)d_in[29];
    const float* bno_m = (const float*)d_in[30], *bno_v = (const float*)d_in[31];
    const float* lout_w = (const float*)d_in[32], *lout_b = (const float*)d_in[33];
    float* out = (float*)d_out;

    float* wsf = (float*)d_ws;
    unsigned short* WCH = (unsigned short*)(wsf + OFF_WC);
    float* XA  = wsf + OFF_XA;
    float* XB  = wsf + OFF_XB;
    float* XC  = wsf + OFF_XC;
    unsigned short* XAT = (unsigned short*)(wsf + OFF_XC);
    unsigned short* XBH = (unsigned short*)(wsf + OFF_XB);   // bf16 x_agg (gemm C)
    float* DEG = wsf + OFF_DEG;
    int* CNT   = (int*)(wsf + OFF_CNT);
    int* CUR   = (int*)(wsf + OFF_CUR);
    int* OFFP  = (int*)(wsf + OFF_OFF);
    int* CSRS  = (int*)(wsf + OFF_CSRS);
    float* CSRN = wsf + OFF_CSRN;
    float* HST  = wsf + OFF_HST;
    float* GIb  = XB;   // GI chunk buffer reuses XB region during the GRU phase

    // CSR + degree build
    k_zero<<<8, 256, 0, stream>>>(CNT, CUR, DEG);
    k_count<<<(ETOT + 255) / 256, 256, 0, stream>>>(edge_idx, edge_w, CNT, DEG);
    k_scan<<<1, 1024, 0, stream>>>(CNT, OFFP);
    k_fill<<<(ETOT + 255) / 256, 256, 0, stream>>>(edge_idx, edge_w, DEG, OFFP, CUR, CSRS, CSRN);

    hipMemsetAsync(WCH, 0, (size_t)2048 * 2048 * 2, stream);
    k_softmax<<<NN, 256, 0, stream>>>(causal_w, WCH);
    // lin_in -> XA [N,T,H] fp32
    k_lin2<<<NN, 256, 0, stream>>>(x_seq, lin_in_w, lin_in_b, XA);
    // transpose+cast: XA -> XAh_t bf16 [4096][2048]
    dim3 tg(THL / 64, 2048 / 64);
    k_tr<<<tg, 256, 0, stream>>>(XA, XAT);
    // x_agg = WCh @ X (MFMA bf16) -> XBH (bf16)
    dim3 gg(THL / 128, 2048 / 128);
    k_gemm_bf<<<gg, 256, 0, stream>>>(WCH, XAT, XBH);
    // fusion -> XC  (X fp32 + XAgg bf16)
    k_fus2<<<NN, 256, 0, stream>>>(XA, XBH, fusion_w, fusion_b, XC);
    // GCN layer 0: XC -> XB (xw) -> XA (agg+bn+relu)
    k_xw2<<<NN, 256, 0, stream>>>(XC, gcn_w0, XB);
    dim3 ag(NN, 4);
    k_agg<<<ag, 256, 0, stream>>>(XB, OFFP, CSRS, CSRN, gcn_b0, bn0_g, bn0_b, bn0_m, bn0_v, XA);
    // GCN layer 1: XA -> XB -> XC
    k_xw2<<<NN, 256, 0, stream>>>(XA, gcn_w1, XB);
    k_agg<<<ag, 256, 0, stream>>>(XB, OFFP, CSRS, CSRN, gcn_b1, bn1_g, bn1_b, bn1_m, bn1_v, XC);

    // GRU layer 0: input XC -> all-t output H0 in XA (chunked over T)
    dim3 gig(NN * CHT / 64, 3);
    for (int c = 0; c < TT / CHT; ++c) {
        k_gi2<<<gig, 256, 0, stream>>>(XC, wih0, bih0, GIb, c * CHT);
        k_rec<<<NN / 4, 256, 0, stream>>>(GIb, whh0, bhh0, HST, XA, c * CHT, c == 0);
    }
    // GRU layer 1: input XA (H0) -> final h in HST
    for (int c = 0; c < TT / CHT; ++c) {
        k_gi2<<<gig, 256, 0, stream>>>(XA, wih1, bih1, GIb, c * CHT);
        k_rec<<<NN / 4, 256, 0, stream>>>(GIb, whh1, bhh1, HST, (float*)nullptr, c * CHT, c == 0);
    }
    // head
    k_head<<<NN / 4, 256, 0, stream>>>(HST, bno_g, bno_b, bno_m, bno_v, lout_w, lout_b, out);
}

// Round 14
// 749.726 us; speedup vs baseline: 1.3832x; 1.0465x over previous
//
#include <hip/hip_runtime.h>
#include <hip/hip_bf16.h>
#include <math.h>

#define TT 64
#define NN 2000
#define FIN 32
#define HH 64
#define CC 10
#define EE 32000
#define ETOT 34000   // E + N self loops
#define THL 4096     // T*H
#define EPSBN 1e-5f

// ---------------- workspace layout (float offsets) ----------------
#define OFF_WC   0u          // WCh bf16 [2048][2048]
#define OFF_XA   4000000u    // 8,192,000  [N,T,H] fp32
#define OFF_XB   12192000u   // 8,192,000  (x_agg bf16 C; then xw scratch)
#define OFF_XC   20384000u   // 8,192,000  (first: XAh_t bf16 [4096][2048]; then fusion out fp32)
#define OFF_DEG  28576000u   // 2048
#define OFF_H1   28578048u   // 128,000 (unused)
#define OFF_CNT  28706048u   // int 2048
#define OFF_CUR  28708096u   // int 2048
#define OFF_OFF  28710144u   // int 2064
#define OFF_CSRS 28712208u   // int 34016
#define OFF_CSRN 28746224u   // float 34016
#define OFF_HST  28780240u   // float 128,000  (GRU h-state)

typedef __attribute__((ext_vector_type(8))) short short8v;
typedef __attribute__((ext_vector_type(4))) float f32x4;

__device__ __forceinline__ float fsigmoid(float x) { return 1.f / (1.f + __expf(-x)); }
__device__ __forceinline__ unsigned short f2bf(float f) {
    __hip_bfloat16 h = __float2bfloat16(f);
    return *reinterpret_cast<unsigned short*>(&h);
}
__device__ __forceinline__ float bf2f(unsigned short u) {
    unsigned int x = ((unsigned int)u) << 16;
    return __int_as_float(x);
}
__device__ __forceinline__ float rdlane(float v, int k) {
    return __int_as_float(__builtin_amdgcn_readlane(__float_as_int(v), k));
}

// ---------------- CSR build ----------------
__global__ void k_zero(int* cnt, int* cur, float* deg) {
    int i = blockIdx.x * 256 + threadIdx.x;
    if (i < 2048) { cnt[i] = 0; cur[i] = 0; deg[i] = 0.f; }
}

__global__ void k_count(const int* __restrict__ ei, const float* __restrict__ ew,
                        int* cnt, float* deg) {
    int e = blockIdx.x * 256 + threadIdx.x;
    if (e < ETOT) {
        int dst; float w;
        if (e < EE) { dst = ei[EE + e]; w = ew[e]; }
        else        { dst = e - EE;     w = 1.f; }
        atomicAdd(&cnt[dst], 1);
        atomicAdd(&deg[dst], w);
    }
}

__global__ __launch_bounds__(1024) void k_scan(const int* __restrict__ cnt, int* off) {
    __shared__ int s[2048];
    int tid = threadIdx.x;
    s[tid]        = (tid        < NN) ? cnt[tid]        : 0;
    s[tid + 1024] = (tid + 1024 < NN) ? cnt[tid + 1024] : 0;
    __syncthreads();
    for (int d = 1; d < 2048; d <<= 1) {
        int idx = (tid + 1) * (d << 1) - 1;
        if (idx < 2048) s[idx] += s[idx - d];
        __syncthreads();
    }
    if (tid == 0) s[2047] = 0;
    __syncthreads();
    for (int d = 1024; d >= 1; d >>= 1) {
        int idx = (tid + 1) * (d << 1) - 1;
        if (idx < 2048) { int t = s[idx - d]; s[idx - d] = s[idx]; s[idx] += t; }
        __syncthreads();
    }
    off[tid] = s[tid];
    off[tid + 1024] = s[tid + 1024];
}

__global__ void k_fill(const int* __restrict__ ei, const float* __restrict__ ew,
                       const float* __restrict__ deg, const int* __restrict__ off,
                       int* cur, int* csr_src, float* csr_nrm) {
    int e = blockIdx.x * 256 + threadIdx.x;
    if (e < ETOT) {
        int src, dst; float w;
        if (e < EE) { src = ei[e]; dst = ei[EE + e]; w = ew[e]; }
        else        { src = dst = e - EE;            w = 1.f; }
        float ds = rsqrtf(fmaxf(deg[src], 1e-12f));
        float dd = rsqrtf(fmaxf(deg[dst], 1e-12f));
        int pos = off[dst] + atomicAdd(&cur[dst], 1);
        csr_src[pos] = src;
        csr_nrm[pos] = ds * w * dd;
    }
}

// ---------------- softmax over causal_weight rows -> bf16 WCh [2048 stride] ----------------
__global__ __launch_bounds__(256) void k_softmax(const float* __restrict__ CW,
                                                 unsigned short* __restrict__ WCH) {
    __shared__ float row[NN];
    __shared__ float red[256];
    int r = blockIdx.x, tid = threadIdx.x;
    const float* in = CW + (size_t)r * NN;
    float mx = -1e30f;
    for (int i = tid; i < NN; i += 256) { float v = in[i]; row[i] = v; mx = fmaxf(mx, v); }
    red[tid] = mx; __syncthreads();
    for (int s = 128; s > 0; s >>= 1) {
        if (tid < s) red[tid] = fmaxf(red[tid], red[tid + s]);
        __syncthreads();
    }
    mx = red[0]; __syncthreads();
    float sm = 0.f;
    for (int i = tid; i < NN; i += 256) { float e = __expf(row[i] - mx); row[i] = e; sm += e; }
    red[tid] = sm; __syncthreads();
    for (int s = 128; s > 0; s >>= 1) {
        if (tid < s) red[tid] += red[tid + s];
        __syncthreads();
    }
    float inv = 1.f / red[0];
    unsigned short* out = WCH + (size_t)r * 2048;
    for (int i = tid; i < 2048; i += 256)
        out[i] = (i < NN) ? f2bf(row[i] * inv) : (unsigned short)0;
}

// ---------------- lin_in as tiled GEMM: rows=(n,t), K=32, 64 cols ----------------
__global__ __launch_bounds__(256) void k_lin2(const float* __restrict__ XS,
                                              const float* __restrict__ W,
                                              const float* __restrict__ b,
                                              float* __restrict__ OUT) {
    __shared__ float Wt[FIN][68];   // [k][o]
    __shared__ float As[FIN][68];   // [k][row]
    int tid = threadIdx.x;
    int n = blockIdx.x;
    for (int i = tid; i < HH * FIN; i += 256) { int o = i >> 5, k = i & 31; Wt[k][o] = W[i]; }
    int row = tid >> 2, kq = tid & 3;   // row = t
    {
        const float4* src = (const float4*)(XS + ((size_t)row * NN + n) * FIN + kq * 8);
        float4 v0 = src[0], v1 = src[1];
        As[kq * 8 + 0][row] = v0.x; As[kq * 8 + 1][row] = v0.y;
        As[kq * 8 + 2][row] = v0.z; As[kq * 8 + 3][row] = v0.w;
        As[kq * 8 + 4][row] = v1.x; As[kq * 8 + 5][row] = v1.y;
        As[kq * 8 + 6][row] = v1.z; As[kq * 8 + 7][row] = v1.w;
    }
    __syncthreads();
    int tx = tid & 15, ty = tid >> 4;
    float acc[4][4] = {};
#pragma unroll
    for (int k = 0; k < FIN; ++k) {
        float4 av = *(const float4*)&As[k][ty * 4];
        float4 wv = *(const float4*)&Wt[k][tx * 4];
        acc[0][0] += av.x * wv.x; acc[0][1] += av.x * wv.y; acc[0][2] += av.x * wv.z; acc[0][3] += av.x * wv.w;
        acc[1][0] += av.y * wv.x; acc[1][1] += av.y * wv.y; acc[1][2] += av.y * wv.z; acc[1][3] += av.y * wv.w;
        acc[2][0] += av.z * wv.x; acc[2][1] += av.z * wv.y; acc[2][2] += av.z * wv.z; acc[2][3] += av.z * wv.w;
        acc[3][0] += av.w * wv.x; acc[3][1] += av.w * wv.y; acc[3][2] += av.w * wv.z; acc[3][3] += av.w * wv.w;
    }
    float4 bv = *(const float4*)(b + tx * 4);
#pragma unroll
    for (int ii = 0; ii < 4; ++ii) {
        float4 o;
        o.x = fmaxf(acc[ii][0] + bv.x, 0.f);
        o.y = fmaxf(acc[ii][1] + bv.y, 0.f);
        o.z = fmaxf(acc[ii][2] + bv.z, 0.f);
        o.w = fmaxf(acc[ii][3] + bv.w, 0.f);
        *(float4*)(OUT + ((size_t)n * TT + ty * 4 + ii) * HH + tx * 4) = o;
    }
}

// ---------------- transpose + bf16 cast ----------------
__global__ __launch_bounds__(256) void k_tr(const float* __restrict__ X,
                                            unsigned short* __restrict__ XT) {
    __shared__ unsigned short tile[64][65];
    int cb = blockIdx.x * 64;
    int kb = blockIdx.y * 64;
    int tid = threadIdx.x;
    int r = tid >> 2, cq = tid & 3;
    const float4* src = (const float4*)(X + (size_t)(kb + r) * THL + cb + cq * 16);
#pragma unroll
    for (int j = 0; j < 4; ++j) {
        float4 v = src[j];
        tile[cq * 16 + j * 4 + 0][r] = f2bf(v.x);
        tile[cq * 16 + j * 4 + 1][r] = f2bf(v.y);
        tile[cq * 16 + j * 4 + 2][r] = f2bf(v.z);
        tile[cq * 16 + j * 4 + 3][r] = f2bf(v.w);
    }
    __syncthreads();
    int cl = tid >> 2, kq = tid & 3;
    unsigned short tmp[16];
#pragma unroll
    for (int j = 0; j < 16; ++j) tmp[j] = tile[cl][kq * 16 + j];
    unsigned short* dst = XT + (size_t)(cb + cl) * 2048 + kb + kq * 16;
    *(uint4*)dst = *(uint4*)tmp;
    *(uint4*)(dst + 8) = *(uint4*)(tmp + 8);
}

// ---------------- bf16 MFMA GEMM: C(bf16)[2000,4096] = WCh @ X (via XAh_t) — FROZEN ----------------
__global__ __launch_bounds__(256, 1) void k_gemm_bf(const unsigned short* __restrict__ A,
                                                    const unsigned short* __restrict__ B,
                                                    unsigned short* __restrict__ CH) {
    __shared__ unsigned short As[128][72];
    __shared__ unsigned short Bs[128][72];
    int tid = threadIdx.x;
    int mb = blockIdx.y * 128, nb = blockIdx.x * 128;
    int w = tid >> 6, lane = tid & 63;
    int wr = w >> 1, wc = w & 1;
    int l15 = lane & 15, l4 = lane >> 4;
    f32x4 acc[4][4] = {};
    int arow = tid >> 3, acol = tid & 7;
    const uint4* ga = (const uint4*)(A + (size_t)(mb + arow) * 2048 + acol * 8);
    const uint4* gb = (const uint4*)(B + (size_t)(nb + arow) * 2048 + acol * 8);
    uint4 va[4], vb[4];
#pragma unroll
    for (int i = 0; i < 4; ++i) { va[i] = ga[(size_t)i * 8192]; vb[i] = gb[(size_t)i * 8192]; }
    ga += 8; gb += 8;
    for (int kt = 0; kt < 32; ++kt) {
        __syncthreads();
#pragma unroll
        for (int i = 0; i < 4; ++i) {
            *(uint4*)&As[arow + i * 32][acol * 8] = va[i];
            *(uint4*)&Bs[arow + i * 32][acol * 8] = vb[i];
        }
        __syncthreads();
        if (kt < 31) {
#pragma unroll
            for (int i = 0; i < 4; ++i) { va[i] = ga[(size_t)i * 8192]; vb[i] = gb[(size_t)i * 8192]; }
            ga += 8; gb += 8;
        }
#pragma unroll
        for (int kk = 0; kk < 2; ++kk) {
            short8v af[4], bfr[4];
#pragma unroll
            for (int f = 0; f < 4; ++f) {
                af[f]  = *(const short8v*)&As[wr * 64 + f * 16 + l15][kk * 32 + l4 * 8];
                bfr[f] = *(const short8v*)&Bs[wc * 64 + f * 16 + l15][kk * 32 + l4 * 8];
            }
#pragma unroll
            for (int fm = 0; fm < 4; ++fm)
#pragma unroll
                for (int fn = 0; fn < 4; ++fn)
                    acc[fm][fn] = __builtin_amdgcn_mfma_f32_16x16x32_bf16(af[fm], bfr[fn], acc[fm][fn], 0, 0, 0);
        }
    }
    unsigned short* epi = (unsigned short*)(&As[0][0]) + (size_t)w * (16 * 72);
    int erow8 = lane >> 3;
    int ecol8 = lane & 7;
#pragma unroll
    for (int fm = 0; fm < 4; ++fm) {
        __syncthreads();
#pragma unroll
        for (int fn = 0; fn < 4; ++fn)
#pragma unroll
            for (int rr = 0; rr < 4; ++rr)
                epi[(l4 * 4 + rr) * 72 + fn * 16 + l15] = f2bf(acc[fm][fn][rr]);
        __syncthreads();
#pragma unroll
        for (int rh = 0; rh < 2; ++rh) {
            int lrow = rh * 8 + erow8;
            int grow = mb + wr * 64 + fm * 16 + lrow;
            if (grow < NN) {
                *(uint4*)(CH + (size_t)grow * THL + nb + wc * 64 + ecol8 * 8)
                    = *(const uint4*)&epi[lrow * 72 + ecol8 * 8];
            }
        }
    }
}

// ---------------- fusion as tiled GEMM: K=128 (X fp32 + XAgg bf16), 64 cols ----------------
__global__ __launch_bounds__(256) void k_fus2(const float* __restrict__ X,
                                              const unsigned short* __restrict__ XAH,
                                              const float* __restrict__ W,
                                              const float* __restrict__ b,
                                              float* __restrict__ OUT) {
    __shared__ float Wt[2 * HH][68];
    __shared__ float As[HH][68];
    int tid = threadIdx.x;
    size_t r0 = (size_t)blockIdx.x * 64;
    for (int i = tid; i < HH * 2 * HH; i += 256) { int o = i >> 7, k = i & 127; Wt[k][o] = W[i]; }
    int row = tid >> 2, kq = tid & 3;
    int tx = tid & 15, ty = tid >> 4;
    float acc[4][4] = {};
    __syncthreads();
    {
        const float4* src = (const float4*)(X + (r0 + row) * HH + kq * 16);
#pragma unroll
        for (int j = 0; j < 4; ++j) {
            float4 v = src[j];
            As[kq * 16 + j * 4 + 0][row] = v.x;
            As[kq * 16 + j * 4 + 1][row] = v.y;
            As[kq * 16 + j * 4 + 2][row] = v.z;
            As[kq * 16 + j * 4 + 3][row] = v.w;
        }
    }
    __syncthreads();
#pragma unroll
    for (int k = 0; k < HH; ++k) {
        float4 av = *(const float4*)&As[k][ty * 4];
        float4 wv = *(const float4*)&Wt[k][tx * 4];
        acc[0][0] += av.x * wv.x; acc[0][1] += av.x * wv.y; acc[0][2] += av.x * wv.z; acc[0][3] += av.x * wv.w;
        acc[1][0] += av.y * wv.x; acc[1][1] += av.y * wv.y; acc[1][2] += av.y * wv.z; acc[1][3] += av.y * wv.w;
        acc[2][0] += av.z * wv.x; acc[2][1] += av.z * wv.y; acc[2][2] += av.z * wv.z; acc[2][3] += av.z * wv.w;
        acc[3][0] += av.w * wv.x; acc[3][1] += av.w * wv.y; acc[3][2] += av.w * wv.z; acc[3][3] += av.w * wv.w;
    }
    __syncthreads();
    {
        const uint4* s = (const uint4*)(XAH + (r0 + row) * HH + kq * 16);
        uint4 u0 = s[0], u1 = s[1];
        unsigned short us[16];
        *(uint4*)us = u0; *(uint4*)(us + 8) = u1;
#pragma unroll
        for (int j = 0; j < 16; ++j)
            As[kq * 16 + j][row] = bf2f(us[j]);
    }
    __syncthreads();
#pragma unroll
    for (int k = 0; k < HH; ++k) {
        float4 av = *(const float4*)&As[k][ty * 4];
        float4 wv = *(const float4*)&Wt[HH + k][tx * 4];
        acc[0][0] += av.x * wv.x; acc[0][1] += av.x * wv.y; acc[0][2] += av.x * wv.z; acc[0][3] += av.x * wv.w;
        acc[1][0] += av.y * wv.x; acc[1][1] += av.y * wv.y; acc[1][2] += av.y * wv.z; acc[1][3] += av.y * wv.w;
        acc[2][0] += av.z * wv.x; acc[2][1] += av.z * wv.y; acc[2][2] += av.z * wv.z; acc[2][3] += av.z * wv.w;
        acc[3][0] += av.w * wv.x; acc[3][1] += av.w * wv.y; acc[3][2] += av.w * wv.z; acc[3][3] += av.w * wv.w;
    }
    float4 bv = *(const float4*)(b + tx * 4);
#pragma unroll
    for (int ii = 0; ii < 4; ++ii) {
        float4 o;
        o.x = fmaxf(acc[ii][0] + bv.x, 0.f);
        o.y = fmaxf(acc[ii][1] + bv.y, 0.f);
        o.z = fmaxf(acc[ii][2] + bv.z, 0.f);
        o.w = fmaxf(acc[ii][3] + bv.w, 0.f);
        *(float4*)(OUT + (r0 + ty * 4 + ii) * HH + tx * 4) = o;
    }
}

// ---------------- GCN xw as tiled GEMM: K=64, 64 cols, no bias ----------------
__global__ __launch_bounds__(256) void k_xw2(const float* __restrict__ IN,
                                             const float* __restrict__ W,
                                             float* __restrict__ OUT) {
    __shared__ float Wt[HH][68];
    __shared__ float As[HH][68];
    int tid = threadIdx.x;
    size_t r0 = (size_t)blockIdx.x * 64;
    for (int i = tid; i < HH * HH; i += 256) { int o = i >> 6, k = i & 63; Wt[k][o] = W[i]; }
    int row = tid >> 2, kq = tid & 3;
    {
        const float4* src = (const float4*)(IN + (r0 + row) * HH + kq * 16);
#pragma unroll
        for (int j = 0; j < 4; ++j) {
            float4 v = src[j];
            As[kq * 16 + j * 4 + 0][row] = v.x;
            As[kq * 16 + j * 4 + 1][row] = v.y;
            As[kq * 16 + j * 4 + 2][row] = v.z;
            As[kq * 16 + j * 4 + 3][row] = v.w;
        }
    }
    __syncthreads();
    int tx = tid & 15, ty = tid >> 4;
    float acc[4][4] = {};
#pragma unroll
    for (int k = 0; k < HH; ++k) {
        float4 av = *(const float4*)&As[k][ty * 4];
        float4 wv = *(const float4*)&Wt[k][tx * 4];
        acc[0][0] += av.x * wv.x; acc[0][1] += av.x * wv.y; acc[0][2] += av.x * wv.z; acc[0][3] += av.x * wv.w;
        acc[1][0] += av.y * wv.x; acc[1][1] += av.y * wv.y; acc[1][2] += av.y * wv.z; acc[1][3] += av.y * wv.w;
        acc[2][0] += av.z * wv.x; acc[2][1] += av.z * wv.y; acc[2][2] += av.z * wv.z; acc[2][3] += av.z * wv.w;
        acc[3][0] += av.w * wv.x; acc[3][1] += av.w * wv.y; acc[3][2] += av.w * wv.z; acc[3][3] += av.w * wv.w;
    }
#pragma unroll
    for (int ii = 0; ii < 4; ++ii) {
        float4 o = make_float4(acc[ii][0], acc[ii][1], acc[ii][2], acc[ii][3]);
        *(float4*)(OUT + (r0 + ty * 4 + ii) * HH + tx * 4) = o;
    }
}

// ---------------- GCN aggregate (CSR) + bias + BN + relu, column-chunked ----------------
__global__ __launch_bounds__(256) void k_agg(const float* __restrict__ XW,
                                             const int* __restrict__ off,
                                             const int* __restrict__ csr_src,
                                             const float* __restrict__ csr_nrm,
                                             const float* __restrict__ bias,
                                             const float* __restrict__ g,
                                             const float* __restrict__ bb,
                                             const float* __restrict__ m,
                                             const float* __restrict__ v,
                                             float* __restrict__ OUT) {
    int dst = blockIdx.x, ch = blockIdx.y, tid = threadIdx.x;
    int base = ch * 1024 + tid * 4;
    float4 acc = make_float4(0.f, 0.f, 0.f, 0.f);
    int beg = off[dst], end = off[dst + 1];
    for (int e = beg; e < end; ++e) {
        int src = csr_src[e];
        float w = csr_nrm[e];
        float4 x = *(const float4*)(XW + (size_t)src * THL + base);
        acc.x += w * x.x; acc.y += w * x.y; acc.z += w * x.z; acc.w += w * x.w;
    }
    int h0 = base & 63;
    float4 bs = *(const float4*)(bias + h0);
    float4 gv = *(const float4*)(g + h0);
    float4 vv = *(const float4*)(v + h0);
    float4 mv = *(const float4*)(m + h0);
    float4 bv = *(const float4*)(bb + h0);
    float4 o;
    o.x = fmaxf((acc.x + bs.x - mv.x) * rsqrtf(vv.x + EPSBN) * gv.x + bv.x, 0.f);
    o.y = fmaxf((acc.y + bs.y - mv.y) * rsqrtf(vv.y + EPSBN) * gv.y + bv.y, 0.f);
    o.z = fmaxf((acc.z + bs.z - mv.z) * rsqrtf(vv.z + EPSBN) * gv.z + bv.z, 0.f);
    o.w = fmaxf((acc.w + bs.w - mv.w) * rsqrtf(vv.w + EPSBN) * gv.w + bv.w, 0.f);
    *(float4*)(OUT + (size_t)dst * THL + base) = o;
}

// ---------------- 4-wave pipelined 2-layer GRU: one block per node ----------------
// wave0: gi0 = x @ wih0^T (no recurrence dep)   -> qgi0 ring
// wave1: h0 recurrence (whh0)                   -> qh0 ring
// wave2: gi1 = h0 @ wih1^T                      -> qgi1 ring
// wave3: h1 recurrence (whh1)                   -> final h
// Each wave holds ONE matrix: 3 rows/lane = 192 VGPRs (k_rec-proven, no spill;
// R12's 6-matrix/384-VGPR version hit the 256 arch-VGPR cap and went to scratch).
// Depth-2 LDS rings, parity-disjoint slots, one __syncthreads per step.
__global__ __launch_bounds__(256, 1) void k_gru4(const float* __restrict__ IN,
                                                 const float* __restrict__ wih0, const float* __restrict__ whh0,
                                                 const float* __restrict__ bih0, const float* __restrict__ bhh0,
                                                 const float* __restrict__ wih1, const float* __restrict__ whh1,
                                                 const float* __restrict__ bih1, const float* __restrict__ bhh1,
                                                 float* __restrict__ hout) {
    __shared__ float qgi0[2][192];
    __shared__ float qh0[2][64];
    __shared__ float qgi1[2][192];
    int tid = threadIdx.x;
    int wid = tid >> 6, j = tid & 63;
    int n = blockIdx.x;
    const float* WM = (wid == 0) ? wih0 : (wid == 1) ? whh0 : (wid == 2) ? wih1 : whh1;
    const float* BM = (wid == 0) ? bih0 : (wid == 1) ? bhh0 : (wid == 2) ? bih1 : bhh1;
    float w0[64], w1[64], w2[64];
    const float4* w4 = (const float4*)WM;
#pragma unroll
    for (int q = 0; q < 16; ++q) {
        float4 a = w4[(size_t)j * 16 + q];
        float4 b = w4[(size_t)(64 + j) * 16 + q];
        float4 c = w4[(size_t)(128 + j) * 16 + q];
        w0[4 * q + 0] = a.x; w0[4 * q + 1] = a.y; w0[4 * q + 2] = a.z; w0[4 * q + 3] = a.w;
        w1[4 * q + 0] = b.x; w1[4 * q + 1] = b.y; w1[4 * q + 2] = b.z; w1[4 * q + 3] = b.w;
        w2[4 * q + 0] = c.x; w2[4 * q + 1] = c.y; w2[4 * q + 2] = c.z; w2[4 * q + 3] = c.w;
    }
    float b0 = BM[j], b1 = BM[64 + j], b2 = BM[128 + j];
    float h = 0.f;                      // recurrence state (waves 1 and 3)
    const float* xb = IN + (size_t)n * TT * HH;
#pragma unroll 1
    for (int t = 0; t < TT + 3; ++t) {
        if (wid == 0) {
            if (t < TT) {
                float xv = xb[t * HH + j];
                float a0 = b0, a1 = b1, a2 = b2;
#pragma unroll
                for (int k = 0; k < 64; ++k) {
                    float s = rdlane(xv, k);
                    a0 += s * w0[k]; a1 += s * w1[k]; a2 += s * w2[k];
                }
                int sl = t & 1;
                qgi0[sl][j] = a0; qgi0[sl][64 + j] = a1; qgi0[sl][128 + j] = a2;
            }
        } else if (wid == 1) {
            int tt = t - 1;
            if (tt >= 0 && tt < TT) {
                int sl = tt & 1;
                float gr = qgi0[sl][j], gz = qgi0[sl][64 + j], gn = qgi0[sl][128 + j];
                float a0 = b0, a1 = b1, a2 = b2;
#pragma unroll
                for (int k = 0; k < 64; ++k) {
                    float s = rdlane(h, k);
                    a0 += s * w0[k]; a1 += s * w1[k]; a2 += s * w2[k];
                }
                float r = fsigmoid(gr + a0);
                float z = fsigmoid(gz + a1);
                float nn2 = tanhf(gn + r * a2);
                h = (1.f - z) * nn2 + z * h;
                qh0[sl][j] = h;
            }
        } else if (wid == 2) {
            int tt = t - 2;
            if (tt >= 0 && tt < TT) {
                int sl = tt & 1;
                float xv = qh0[sl][j];
                float a0 = b0, a1 = b1, a2 = b2;
#pragma unroll
                for (int k = 0; k < 64; ++k) {
                    float s = rdlane(xv, k);
                    a0 += s * w0[k]; a1 += s * w1[k]; a2 += s * w2[k];
                }
                qgi1[sl][j] = a0; qgi1[sl][64 + j] = a1; qgi1[sl][128 + j] = a2;
            }
        } else {
            int tt = t - 3;
            if (tt >= 0 && tt < TT) {
                int sl = tt & 1;
                float gr = qgi1[sl][j], gz = qgi1[sl][64 + j], gn = qgi1[sl][128 + j];
                float a0 = b0, a1 = b1, a2 = b2;
#pragma unroll
                for (int k = 0; k < 64; ++k) {
                    float s = rdlane(h, k);
                    a0 += s * w0[k]; a1 += s * w1[k]; a2 += s * w2[k];
                }
                float r = fsigmoid(gr + a0);
                float z = fsigmoid(gz + a1);
                float nn2 = tanhf(gn + r * a2);
                h = (1.f - z) * nn2 + z * h;
            }
        }
        __syncthreads();
    }
    if (wid == 3) hout[(size_t)n * HH + j] = h;
}

// ---------------- head: BN + relu + linear + log_softmax ----------------
__global__ __launch_bounds__(256) void k_head(const float* __restrict__ Hf,
                                              const float* __restrict__ g, const float* __restrict__ b,
                                              const float* __restrict__ m, const float* __restrict__ v,
                                              const float* __restrict__ W, const float* __restrict__ wb,
                                              float* __restrict__ out) {
    __shared__ float hb[4][HH];
    __shared__ float lg[4][CC];
    int tid = threadIdx.x;
    int n0 = blockIdx.x * 4;
    int wv = tid >> 6, lane = tid & 63;
    int n = n0 + wv;
    float x = Hf[(size_t)n * HH + lane];
    x = (x - m[lane]) * rsqrtf(v[lane] + EPSBN) * g[lane] + b[lane];
    hb[wv][lane] = fmaxf(x, 0.f);
    __syncthreads();
    if (tid < 4 * CC) {
        int nn = tid / CC, c = tid % CC;
        float acc = wb[c];
        for (int f = 0; f < HH; ++f) acc += hb[nn][f] * W[c * HH + f];
        lg[nn][c] = acc;
    }
    __syncthreads();
    if (tid < 4 * CC) {
        int nn = tid / CC, c = tid % CC;
        float mx = -1e30f;
#pragma unroll
        for (int i = 0; i < CC; ++i) mx = fmaxf(mx, lg[nn][i]);
        float s = 0.f;
#pragma unroll
        for (int i = 0; i < CC; ++i) s += __expf(lg[nn][i] - mx);
        out[(size_t)(n0 + nn) * CC + c] = lg[nn][c] - mx - __logf(s);
    }
}

// ---------------- launch ----------------
extern "C" void kernel_launch(void* const* d_in, const int* in_sizes, int n_in,
                              void* d_out, int out_size, void* d_ws, size_t ws_size,
                              hipStream_t stream) {
    const float* x_seq     = (const float*)d_in[0];
    const int*   edge_idx  = (const int*)d_in[1];
    const float* edge_w    = (const float*)d_in[2];
    const float* causal_w  = (const float*)d_in[3];
    const float* lin_in_w  = (const float*)d_in[4];
    const float* lin_in_b  = (const float*)d_in[5];
    const float* fusion_w  = (const float*)d_in[6];
    const float* fusion_b  = (const float*)d_in[7];
    const float* gcn_w0    = (const float*)d_in[8];
    const float* gcn_b0    = (const float*)d_in[9];
    const float* gcn_w1    = (const float*)d_in[10];
    const float* gcn_b1    = (const float*)d_in[11];
    const float* bn0_g = (const float*)d_in[12], *bn0_b = (const float*)d_in[13];
    const float* bn0_m = (const float*)d_in[14], *bn0_v = (const float*)d_in[15];
    const float* bn1_g = (const float*)d_in[16], *bn1_b = (const float*)d_in[17];
    const float* bn1_m = (const float*)d_in[18], *bn1_v = (const float*)d_in[19];
    const float* wih0 = (const float*)d_in[20], *whh0 = (const float*)d_in[21];
    const float* bih0 = (const float*)d_in[22], *bhh0 = (const float*)d_in[23];
    const float* wih1 = (const float*)d_in[24], *whh1 = (const float*)d_in[25];
    const float* bih1 = (const float*)d_in[26], *bhh1 = (const float*)d_in[27];
    const float* bno_g = (const float*)d_in[28], *bno_b = (const float*)d_in[29];
    const float* bno_m = (const float*)d_in[30], *bno_v = (const float*)d_in[31];
    const float* lout_w = (const float*)d_in[32], *lout_b = (const float*)d_in[33];
    float* out = (float*)d_out;

    float* wsf = (float*)d_ws;
    unsigned short* WCH = (unsigned short*)(wsf + OFF_WC);
    float* XA  = wsf + OFF_XA;
    float* XB  = wsf + OFF_XB;
    float* XC  = wsf + OFF_XC;
    unsigned short* XAT = (unsigned short*)(wsf + OFF_XC);
    unsigned short* XBH = (unsigned short*)(wsf + OFF_XB);   // bf16 x_agg (gemm C)
    float* DEG = wsf + OFF_DEG;
    int* CNT   = (int*)(wsf + OFF_CNT);
    int* CUR   = (int*)(wsf + OFF_CUR);
    int* OFFP  = (int*)(wsf + OFF_OFF);
    int* CSRS  = (int*)(wsf + OFF_CSRS);
    float* CSRN = wsf + OFF_CSRN;
    float* HST  = wsf + OFF_HST;

    // CSR + degree build
    k_zero<<<8, 256, 0, stream>>>(CNT, CUR, DEG);
    k_count<<<(ETOT + 255) / 256, 256, 0, stream>>>(edge_idx, edge_w, CNT, DEG);
    k_scan<<<1, 1024, 0, stream>>>(CNT, OFFP);
    k_fill<<<(ETOT + 255) / 256, 256, 0, stream>>>(edge_idx, edge_w, DEG, OFFP, CUR, CSRS, CSRN);

    hipMemsetAsync(WCH, 0, (size_t)2048 * 2048 * 2, stream);
    k_softmax<<<NN, 256, 0, stream>>>(causal_w, WCH);
    // lin_in -> XA [N,T,H] fp32
    k_lin2<<<NN, 256, 0, stream>>>(x_seq, lin_in_w, lin_in_b, XA);
    // transpose+cast: XA -> XAh_t bf16 [4096][2048]
    dim3 tg(THL / 64, 2048 / 64);
    k_tr<<<tg, 256, 0, stream>>>(XA, XAT);
    // x_agg = WCh @ X (MFMA bf16) -> XBH (bf16)
    dim3 gg(THL / 128, 2048 / 128);
    k_gemm_bf<<<gg, 256, 0, stream>>>(WCH, XAT, XBH);
    // fusion -> XC  (X fp32 + XAgg bf16)
    k_fus2<<<NN, 256, 0, stream>>>(XA, XBH, fusion_w, fusion_b, XC);
    // GCN layer 0: XC -> XB (xw) -> XA (agg+bn+relu)
    k_xw2<<<NN, 256, 0, stream>>>(XC, gcn_w0, XB);
    dim3 ag(NN, 4);
    k_agg<<<ag, 256, 0, stream>>>(XB, OFFP, CSRS, CSRN, gcn_b0, bn0_g, bn0_b, bn0_m, bn0_v, XA);
    // GCN layer 1: XA -> XB -> XC
    k_xw2<<<NN, 256, 0, stream>>>(XA, gcn_w1, XB);
    k_agg<<<ag, 256, 0, stream>>>(XB, OFFP, CSRS, CSRN, gcn_b1, bn1_g, bn1_b, bn1_m, bn1_v, XC);

    // 4-wave pipelined 2-layer GRU: XC -> final h in HST (single dispatch)
    k_gru4<<<NN, 256, 0, stream>>>(XC, wih0, whh0, bih0, bhh0,
                                   wih1, whh1, bih1, bhh1, HST);

    // head
    k_head<<<NN / 4, 256, 0, stream>>>(HST, bno_g, bno_b, bno_m, bno_v, lout_w, lout_b, out);
}

// Round 15
// 734.519 us; speedup vs baseline: 1.4119x; 1.0207x over previous
//
#include <hip/hip_runtime.h>
#include <hip/hip_bf16.h>
#include <math.h>

#define TT 64
#define NN 2000
#define FIN 32
#define HH 64
#define CC 10
#define EE 32000
#define ETOT 34000   // E + N self loops
#define THL 4096     // T*H
#define EPSBN 1e-5f

// ---------------- workspace layout (float offsets) ----------------
#define OFF_WC   0u          // WCh bf16 [2048][2048]
#define OFF_XA   4000000u    // 8,192,000  [N,T,H] fp32
#define OFF_XB   12192000u   // 8,192,000  (x_agg bf16 C; then xw scratch)
#define OFF_XC   20384000u   // 8,192,000  (first: XAh_t bf16 [4096][2048]; then fusion out fp32)
#define OFF_DEG  28576000u   // 2048
#define OFF_H1   28578048u   // 128,000 (unused)
#define OFF_CNT  28706048u   // int 2048
#define OFF_CUR  28708096u   // int 2048
#define OFF_OFF  28710144u   // int 2064
#define OFF_CSRS 28712208u   // int 34016
#define OFF_CSRN 28746224u   // float 34016
#define OFF_HST  28780240u   // float 128,000  (GRU h-state)

typedef __attribute__((ext_vector_type(8))) short short8v;
typedef __attribute__((ext_vector_type(4))) float f32x4;

__device__ __forceinline__ float fsigmoid(float x) { return 1.f / (1.f + __expf(-x)); }
__device__ __forceinline__ unsigned short f2bf(float f) {
    __hip_bfloat16 h = __float2bfloat16(f);
    return *reinterpret_cast<unsigned short*>(&h);
}
__device__ __forceinline__ float bf2f(unsigned short u) {
    unsigned int x = ((unsigned int)u) << 16;
    return __int_as_float(x);
}
__device__ __forceinline__ float rdlane(float v, int k) {
    return __int_as_float(__builtin_amdgcn_readlane(__float_as_int(v), k));
}

// ---------------- CSR build ----------------
__global__ void k_zero(int* cnt, int* cur, float* deg) {
    int i = blockIdx.x * 256 + threadIdx.x;
    if (i < 2048) { cnt[i] = 0; cur[i] = 0; deg[i] = 0.f; }
}

__global__ void k_count(const int* __restrict__ ei, const float* __restrict__ ew,
                        int* cnt, float* deg) {
    int e = blockIdx.x * 256 + threadIdx.x;
    if (e < ETOT) {
        int dst; float w;
        if (e < EE) { dst = ei[EE + e]; w = ew[e]; }
        else        { dst = e - EE;     w = 1.f; }
        atomicAdd(&cnt[dst], 1);
        atomicAdd(&deg[dst], w);
    }
}

__global__ __launch_bounds__(1024) void k_scan(const int* __restrict__ cnt, int* off) {
    __shared__ int s[2048];
    int tid = threadIdx.x;
    s[tid]        = (tid        < NN) ? cnt[tid]        : 0;
    s[tid + 1024] = (tid + 1024 < NN) ? cnt[tid + 1024] : 0;
    __syncthreads();
    for (int d = 1; d < 2048; d <<= 1) {
        int idx = (tid + 1) * (d << 1) - 1;
        if (idx < 2048) s[idx] += s[idx - d];
        __syncthreads();
    }
    if (tid == 0) s[2047] = 0;
    __syncthreads();
    for (int d = 1024; d >= 1; d >>= 1) {
        int idx = (tid + 1) * (d << 1) - 1;
        if (idx < 2048) { int t = s[idx - d]; s[idx - d] = s[idx]; s[idx] += t; }
        __syncthreads();
    }
    off[tid] = s[tid];
    off[tid + 1024] = s[tid + 1024];
}

__global__ void k_fill(const int* __restrict__ ei, const float* __restrict__ ew,
                       const float* __restrict__ deg, const int* __restrict__ off,
                       int* cur, int* csr_src, float* csr_nrm) {
    int e = blockIdx.x * 256 + threadIdx.x;
    if (e < ETOT) {
        int src, dst; float w;
        if (e < EE) { src = ei[e]; dst = ei[EE + e]; w = ew[e]; }
        else        { src = dst = e - EE;            w = 1.f; }
        float ds = rsqrtf(fmaxf(deg[src], 1e-12f));
        float dd = rsqrtf(fmaxf(deg[dst], 1e-12f));
        int pos = off[dst] + atomicAdd(&cur[dst], 1);
        csr_src[pos] = src;
        csr_nrm[pos] = ds * w * dd;
    }
}

// ---------------- softmax over causal_weight rows -> bf16 WCh [2048 stride] ----------------
__global__ __launch_bounds__(256) void k_softmax(const float* __restrict__ CW,
                                                 unsigned short* __restrict__ WCH) {
    __shared__ float row[NN];
    __shared__ float red[256];
    int r = blockIdx.x, tid = threadIdx.x;
    const float* in = CW + (size_t)r * NN;
    float mx = -1e30f;
    for (int i = tid; i < NN; i += 256) { float v = in[i]; row[i] = v; mx = fmaxf(mx, v); }
    red[tid] = mx; __syncthreads();
    for (int s = 128; s > 0; s >>= 1) {
        if (tid < s) red[tid] = fmaxf(red[tid], red[tid + s]);
        __syncthreads();
    }
    mx = red[0]; __syncthreads();
    float sm = 0.f;
    for (int i = tid; i < NN; i += 256) { float e = __expf(row[i] - mx); row[i] = e; sm += e; }
    red[tid] = sm; __syncthreads();
    for (int s = 128; s > 0; s >>= 1) {
        if (tid < s) red[tid] += red[tid + s];
        __syncthreads();
    }
    float inv = 1.f / red[0];
    unsigned short* out = WCH + (size_t)r * 2048;
    for (int i = tid; i < 2048; i += 256)
        out[i] = (i < NN) ? f2bf(row[i] * inv) : (unsigned short)0;
}

// ---------------- lin_in as tiled GEMM: rows=(n,t), K=32, 64 cols ----------------
__global__ __launch_bounds__(256) void k_lin2(const float* __restrict__ XS,
                                              const float* __restrict__ W,
                                              const float* __restrict__ b,
                                              float* __restrict__ OUT) {
    __shared__ float Wt[FIN][68];   // [k][o]
    __shared__ float As[FIN][68];   // [k][row]
    int tid = threadIdx.x;
    int n = blockIdx.x;
    for (int i = tid; i < HH * FIN; i += 256) { int o = i >> 5, k = i & 31; Wt[k][o] = W[i]; }
    int row = tid >> 2, kq = tid & 3;   // row = t
    {
        const float4* src = (const float4*)(XS + ((size_t)row * NN + n) * FIN + kq * 8);
        float4 v0 = src[0], v1 = src[1];
        As[kq * 8 + 0][row] = v0.x; As[kq * 8 + 1][row] = v0.y;
        As[kq * 8 + 2][row] = v0.z; As[kq * 8 + 3][row] = v0.w;
        As[kq * 8 + 4][row] = v1.x; As[kq * 8 + 5][row] = v1.y;
        As[kq * 8 + 6][row] = v1.z; As[kq * 8 + 7][row] = v1.w;
    }
    __syncthreads();
    int tx = tid & 15, ty = tid >> 4;
    float acc[4][4] = {};
#pragma unroll
    for (int k = 0; k < FIN; ++k) {
        float4 av = *(const float4*)&As[k][ty * 4];
        float4 wv = *(const float4*)&Wt[k][tx * 4];
        acc[0][0] += av.x * wv.x; acc[0][1] += av.x * wv.y; acc[0][2] += av.x * wv.z; acc[0][3] += av.x * wv.w;
        acc[1][0] += av.y * wv.x; acc[1][1] += av.y * wv.y; acc[1][2] += av.y * wv.z; acc[1][3] += av.y * wv.w;
        acc[2][0] += av.z * wv.x; acc[2][1] += av.z * wv.y; acc[2][2] += av.z * wv.z; acc[2][3] += av.z * wv.w;
        acc[3][0] += av.w * wv.x; acc[3][1] += av.w * wv.y; acc[3][2] += av.w * wv.z; acc[3][3] += av.w * wv.w;
    }
    float4 bv = *(const float4*)(b + tx * 4);
#pragma unroll
    for (int ii = 0; ii < 4; ++ii) {
        float4 o;
        o.x = fmaxf(acc[ii][0] + bv.x, 0.f);
        o.y = fmaxf(acc[ii][1] + bv.y, 0.f);
        o.z = fmaxf(acc[ii][2] + bv.z, 0.f);
        o.w = fmaxf(acc[ii][3] + bv.w, 0.f);
        *(float4*)(OUT + ((size_t)n * TT + ty * 4 + ii) * HH + tx * 4) = o;
    }
}

// ---------------- transpose + bf16 cast ----------------
__global__ __launch_bounds__(256) void k_tr(const float* __restrict__ X,
                                            unsigned short* __restrict__ XT) {
    __shared__ unsigned short tile[64][65];
    int cb = blockIdx.x * 64;
    int kb = blockIdx.y * 64;
    int tid = threadIdx.x;
    int r = tid >> 2, cq = tid & 3;
    const float4* src = (const float4*)(X + (size_t)(kb + r) * THL + cb + cq * 16);
#pragma unroll
    for (int j = 0; j < 4; ++j) {
        float4 v = src[j];
        tile[cq * 16 + j * 4 + 0][r] = f2bf(v.x);
        tile[cq * 16 + j * 4 + 1][r] = f2bf(v.y);
        tile[cq * 16 + j * 4 + 2][r] = f2bf(v.z);
        tile[cq * 16 + j * 4 + 3][r] = f2bf(v.w);
    }
    __syncthreads();
    int cl = tid >> 2, kq = tid & 3;
    unsigned short tmp[16];
#pragma unroll
    for (int j = 0; j < 16; ++j) tmp[j] = tile[cl][kq * 16 + j];
    unsigned short* dst = XT + (size_t)(cb + cl) * 2048 + kb + kq * 16;
    *(uint4*)dst = *(uint4*)tmp;
    *(uint4*)(dst + 8) = *(uint4*)(tmp + 8);
}

// ---------------- bf16 MFMA GEMM: C(bf16)[2000,4096] = WCh @ X (via XAh_t) — FROZEN ----------------
__global__ __launch_bounds__(256, 1) void k_gemm_bf(const unsigned short* __restrict__ A,
                                                    const unsigned short* __restrict__ B,
                                                    unsigned short* __restrict__ CH) {
    __shared__ unsigned short As[128][72];
    __shared__ unsigned short Bs[128][72];
    int tid = threadIdx.x;
    int mb = blockIdx.y * 128, nb = blockIdx.x * 128;
    int w = tid >> 6, lane = tid & 63;
    int wr = w >> 1, wc = w & 1;
    int l15 = lane & 15, l4 = lane >> 4;
    f32x4 acc[4][4] = {};
    int arow = tid >> 3, acol = tid & 7;
    const uint4* ga = (const uint4*)(A + (size_t)(mb + arow) * 2048 + acol * 8);
    const uint4* gb = (const uint4*)(B + (size_t)(nb + arow) * 2048 + acol * 8);
    uint4 va[4], vb[4];
#pragma unroll
    for (int i = 0; i < 4; ++i) { va[i] = ga[(size_t)i * 8192]; vb[i] = gb[(size_t)i * 8192]; }
    ga += 8; gb += 8;
    for (int kt = 0; kt < 32; ++kt) {
        __syncthreads();
#pragma unroll
        for (int i = 0; i < 4; ++i) {
            *(uint4*)&As[arow + i * 32][acol * 8] = va[i];
            *(uint4*)&Bs[arow + i * 32][acol * 8] = vb[i];
        }
        __syncthreads();
        if (kt < 31) {
#pragma unroll
            for (int i = 0; i < 4; ++i) { va[i] = ga[(size_t)i * 8192]; vb[i] = gb[(size_t)i * 8192]; }
            ga += 8; gb += 8;
        }
#pragma unroll
        for (int kk = 0; kk < 2; ++kk) {
            short8v af[4], bfr[4];
#pragma unroll
            for (int f = 0; f < 4; ++f) {
                af[f]  = *(const short8v*)&As[wr * 64 + f * 16 + l15][kk * 32 + l4 * 8];
                bfr[f] = *(const short8v*)&Bs[wc * 64 + f * 16 + l15][kk * 32 + l4 * 8];
            }
#pragma unroll
            for (int fm = 0; fm < 4; ++fm)
#pragma unroll
                for (int fn = 0; fn < 4; ++fn)
                    acc[fm][fn] = __builtin_amdgcn_mfma_f32_16x16x32_bf16(af[fm], bfr[fn], acc[fm][fn], 0, 0, 0);
        }
    }
    unsigned short* epi = (unsigned short*)(&As[0][0]) + (size_t)w * (16 * 72);
    int erow8 = lane >> 3;
    int ecol8 = lane & 7;
#pragma unroll
    for (int fm = 0; fm < 4; ++fm) {
        __syncthreads();
#pragma unroll
        for (int fn = 0; fn < 4; ++fn)
#pragma unroll
            for (int rr = 0; rr < 4; ++rr)
                epi[(l4 * 4 + rr) * 72 + fn * 16 + l15] = f2bf(acc[fm][fn][rr]);
        __syncthreads();
#pragma unroll
        for (int rh = 0; rh < 2; ++rh) {
            int lrow = rh * 8 + erow8;
            int grow = mb + wr * 64 + fm * 16 + lrow;
            if (grow < NN) {
                *(uint4*)(CH + (size_t)grow * THL + nb + wc * 64 + ecol8 * 8)
                    = *(const uint4*)&epi[lrow * 72 + ecol8 * 8];
            }
        }
    }
}

// ---------------- fusion as tiled GEMM: K=128 (X fp32 + XAgg bf16), 64 cols ----------------
__global__ __launch_bounds__(256) void k_fus2(const float* __restrict__ X,
                                              const unsigned short* __restrict__ XAH,
                                              const float* __restrict__ W,
                                              const float* __restrict__ b,
                                              float* __restrict__ OUT) {
    __shared__ float Wt[2 * HH][68];
    __shared__ float As[HH][68];
    int tid = threadIdx.x;
    size_t r0 = (size_t)blockIdx.x * 64;
    for (int i = tid; i < HH * 2 * HH; i += 256) { int o = i >> 7, k = i & 127; Wt[k][o] = W[i]; }
    int row = tid >> 2, kq = tid & 3;
    int tx = tid & 15, ty = tid >> 4;
    float acc[4][4] = {};
    __syncthreads();
    {
        const float4* src = (const float4*)(X + (r0 + row) * HH + kq * 16);
#pragma unroll
        for (int j = 0; j < 4; ++j) {
            float4 v = src[j];
            As[kq * 16 + j * 4 + 0][row] = v.x;
            As[kq * 16 + j * 4 + 1][row] = v.y;
            As[kq * 16 + j * 4 + 2][row] = v.z;
            As[kq * 16 + j * 4 + 3][row] = v.w;
        }
    }
    __syncthreads();
#pragma unroll
    for (int k = 0; k < HH; ++k) {
        float4 av = *(const float4*)&As[k][ty * 4];
        float4 wv = *(const float4*)&Wt[k][tx * 4];
        acc[0][0] += av.x * wv.x; acc[0][1] += av.x * wv.y; acc[0][2] += av.x * wv.z; acc[0][3] += av.x * wv.w;
        acc[1][0] += av.y * wv.x; acc[1][1] += av.y * wv.y; acc[1][2] += av.y * wv.z; acc[1][3] += av.y * wv.w;
        acc[2][0] += av.z * wv.x; acc[2][1] += av.z * wv.y; acc[2][2] += av.z * wv.z; acc[2][3] += av.z * wv.w;
        acc[3][0] += av.w * wv.x; acc[3][1] += av.w * wv.y; acc[3][2] += av.w * wv.z; acc[3][3] += av.w * wv.w;
    }
    __syncthreads();
    {
        const uint4* s = (const uint4*)(XAH + (r0 + row) * HH + kq * 16);
        uint4 u0 = s[0], u1 = s[1];
        unsigned short us[16];
        *(uint4*)us = u0; *(uint4*)(us + 8) = u1;
#pragma unroll
        for (int j = 0; j < 16; ++j)
            As[kq * 16 + j][row] = bf2f(us[j]);
    }
    __syncthreads();
#pragma unroll
    for (int k = 0; k < HH; ++k) {
        float4 av = *(const float4*)&As[k][ty * 4];
        float4 wv = *(const float4*)&Wt[HH + k][tx * 4];
        acc[0][0] += av.x * wv.x; acc[0][1] += av.x * wv.y; acc[0][2] += av.x * wv.z; acc[0][3] += av.x * wv.w;
        acc[1][0] += av.y * wv.x; acc[1][1] += av.y * wv.y; acc[1][2] += av.y * wv.z; acc[1][3] += av.y * wv.w;
        acc[2][0] += av.z * wv.x; acc[2][1] += av.z * wv.y; acc[2][2] += av.z * wv.z; acc[2][3] += av.z * wv.w;
        acc[3][0] += av.w * wv.x; acc[3][1] += av.w * wv.y; acc[3][2] += av.w * wv.z; acc[3][3] += av.w * wv.w;
    }
    float4 bv = *(const float4*)(b + tx * 4);
#pragma unroll
    for (int ii = 0; ii < 4; ++ii) {
        float4 o;
        o.x = fmaxf(acc[ii][0] + bv.x, 0.f);
        o.y = fmaxf(acc[ii][1] + bv.y, 0.f);
        o.z = fmaxf(acc[ii][2] + bv.z, 0.f);
        o.w = fmaxf(acc[ii][3] + bv.w, 0.f);
        *(float4*)(OUT + (r0 + ty * 4 + ii) * HH + tx * 4) = o;
    }
}

// ---------------- GCN xw as tiled GEMM: K=64, 64 cols, no bias ----------------
__global__ __launch_bounds__(256) void k_xw2(const float* __restrict__ IN,
                                             const float* __restrict__ W,
                                             float* __restrict__ OUT) {
    __shared__ float Wt[HH][68];
    __shared__ float As[HH][68];
    int tid = threadIdx.x;
    size_t r0 = (size_t)blockIdx.x * 64;
    for (int i = tid; i < HH * HH; i += 256) { int o = i >> 6, k = i & 63; Wt[k][o] = W[i]; }
    int row = tid >> 2, kq = tid & 3;
    {
        const float4* src = (const float4*)(IN + (r0 + row) * HH + kq * 16);
#pragma unroll
        for (int j = 0; j < 4; ++j) {
            float4 v = src[j];
            As[kq * 16 + j * 4 + 0][row] = v.x;
            As[kq * 16 + j * 4 + 1][row] = v.y;
            As[kq * 16 + j * 4 + 2][row] = v.z;
            As[kq * 16 + j * 4 + 3][row] = v.w;
        }
    }
    __syncthreads();
    int tx = tid & 15, ty = tid >> 4;
    float acc[4][4] = {};
#pragma unroll
    for (int k = 0; k < HH; ++k) {
        float4 av = *(const float4*)&As[k][ty * 4];
        float4 wv = *(const float4*)&Wt[k][tx * 4];
        acc[0][0] += av.x * wv.x; acc[0][1] += av.x * wv.y; acc[0][2] += av.x * wv.z; acc[0][3] += av.x * wv.w;
        acc[1][0] += av.y * wv.x; acc[1][1] += av.y * wv.y; acc[1][2] += av.y * wv.z; acc[1][3] += av.y * wv.w;
        acc[2][0] += av.z * wv.x; acc[2][1] += av.z * wv.y; acc[2][2] += av.z * wv.z; acc[2][3] += av.z * wv.w;
        acc[3][0] += av.w * wv.x; acc[3][1] += av.w * wv.y; acc[3][2] += av.w * wv.z; acc[3][3] += av.w * wv.w;
    }
#pragma unroll
    for (int ii = 0; ii < 4; ++ii) {
        float4 o = make_float4(acc[ii][0], acc[ii][1], acc[ii][2], acc[ii][3]);
        *(float4*)(OUT + (r0 + ty * 4 + ii) * HH + tx * 4) = o;
    }
}

// ---------------- GCN aggregate (CSR) + bias + BN + relu, column-chunked ----------------
__global__ __launch_bounds__(256) void k_agg(const float* __restrict__ XW,
                                             const int* __restrict__ off,
                                             const int* __restrict__ csr_src,
                                             const float* __restrict__ csr_nrm,
                                             const float* __restrict__ bias,
                                             const float* __restrict__ g,
                                             const float* __restrict__ bb,
                                             const float* __restrict__ m,
                                             const float* __restrict__ v,
                                             float* __restrict__ OUT) {
    int dst = blockIdx.x, ch = blockIdx.y, tid = threadIdx.x;
    int base = ch * 1024 + tid * 4;
    float4 acc = make_float4(0.f, 0.f, 0.f, 0.f);
    int beg = off[dst], end = off[dst + 1];
    for (int e = beg; e < end; ++e) {
        int src = csr_src[e];
        float w = csr_nrm[e];
        float4 x = *(const float4*)(XW + (size_t)src * THL + base);
        acc.x += w * x.x; acc.y += w * x.y; acc.z += w * x.z; acc.w += w * x.w;
    }
    int h0 = base & 63;
    float4 bs = *(const float4*)(bias + h0);
    float4 gv = *(const float4*)(g + h0);
    float4 vv = *(const float4*)(v + h0);
    float4 mv = *(const float4*)(m + h0);
    float4 bv = *(const float4*)(bb + h0);
    float4 o;
    o.x = fmaxf((acc.x + bs.x - mv.x) * rsqrtf(vv.x + EPSBN) * gv.x + bv.x, 0.f);
    o.y = fmaxf((acc.y + bs.y - mv.y) * rsqrtf(vv.y + EPSBN) * gv.y + bv.y, 0.f);
    o.z = fmaxf((acc.z + bs.z - mv.z) * rsqrtf(vv.z + EPSBN) * gv.z + bv.z, 0.f);
    o.w = fmaxf((acc.w + bs.w - mv.w) * rsqrtf(vv.w + EPSBN) * gv.w + bv.w, 0.f);
    *(float4*)(OUT + (size_t)dst * THL + base) = o;
}

// ---------------- 4-wave pipelined 2-layer GRU: one block per node ----------------
// R15: UNIFORM loop body — one matvec instance shared by all 4 waves (src select
// is outside the unrolled loop). R14's 4-way-branched version instantiated the
// 64-iter unrolled loop 4x; unroll heuristic bailed -> runtime-indexed w[k] ->
// scratch (VGPR_Count=108, 384us). Single instance => full unroll, w in VGPRs.
__global__ __launch_bounds__(256, 1) void k_gru4(const float* __restrict__ IN,
                                                 const float* __restrict__ wih0, const float* __restrict__ whh0,
                                                 const float* __restrict__ bih0, const float* __restrict__ bhh0,
                                                 const float* __restrict__ wih1, const float* __restrict__ whh1,
                                                 const float* __restrict__ bih1, const float* __restrict__ bhh1,
                                                 float* __restrict__ hout) {
    __shared__ float qgi0[2][192];
    __shared__ float qh0[2][64];
    __shared__ float qgi1[2][192];
    int tid = threadIdx.x;
    int wid = tid >> 6, j = tid & 63;
    int n = blockIdx.x;
    const float* WM = (wid == 0) ? wih0 : (wid == 1) ? whh0 : (wid == 2) ? wih1 : whh1;
    const float* BM = (wid == 0) ? bih0 : (wid == 1) ? bhh0 : (wid == 2) ? bih1 : bhh1;
    float w0[64], w1[64], w2[64];
    const float4* w4 = (const float4*)WM;
#pragma unroll
    for (int q = 0; q < 16; ++q) {
        float4 a = w4[(size_t)j * 16 + q];
        float4 b = w4[(size_t)(64 + j) * 16 + q];
        float4 c = w4[(size_t)(128 + j) * 16 + q];
        w0[4 * q + 0] = a.x; w0[4 * q + 1] = a.y; w0[4 * q + 2] = a.z; w0[4 * q + 3] = a.w;
        w1[4 * q + 0] = b.x; w1[4 * q + 1] = b.y; w1[4 * q + 2] = b.z; w1[4 * q + 3] = b.w;
        w2[4 * q + 0] = c.x; w2[4 * q + 1] = c.y; w2[4 * q + 2] = c.z; w2[4 * q + 3] = c.w;
    }
    float b0 = BM[j], b1 = BM[64 + j], b2 = BM[128 + j];
    float h = 0.f;
    const float* xb = IN + (size_t)n * TT * HH;
    // zero rings (avoid garbage in warm-up matvecs)
    for (int i = tid; i < 2 * 192; i += 256) { ((float*)qgi0)[i] = 0.f; ((float*)qgi1)[i] = 0.f; }
    if (tid < 128) ((float*)qh0)[tid] = 0.f;
    __syncthreads();
#pragma unroll 1
    for (int t = 0; t < TT + 3; ++t) {
        int tt = t - wid;               // this wave's logical timestep
        bool act = (tt >= 0) && (tt < TT);
        int sl = tt & 1;
        float src;
        if (wid == 0)      src = act ? xb[(size_t)tt * HH + j] : 0.f;
        else if (wid == 1) src = h;
        else if (wid == 2) src = qh0[sl][j];
        else               src = h;
        // ---- single shared matvec instance (full unroll, w in VGPRs) ----
        float a0 = b0, a1 = b1, a2 = b2;
#pragma unroll
        for (int k = 0; k < 64; ++k) {
            float s = rdlane(src, k);
            a0 += s * w0[k]; a1 += s * w1[k]; a2 += s * w2[k];
        }
        if (act) {
            if (wid == 0) {
                qgi0[sl][j] = a0; qgi0[sl][64 + j] = a1; qgi0[sl][128 + j] = a2;
            } else if (wid == 1) {
                float gr = qgi0[sl][j], gz = qgi0[sl][64 + j], gn = qgi0[sl][128 + j];
                float r = fsigmoid(gr + a0);
                float z = fsigmoid(gz + a1);
                float nn2 = tanhf(gn + r * a2);
                h = (1.f - z) * nn2 + z * h;
                qh0[sl][j] = h;
            } else if (wid == 2) {
                qgi1[sl][j] = a0; qgi1[sl][64 + j] = a1; qgi1[sl][128 + j] = a2;
            } else {
                float gr = qgi1[sl][j], gz = qgi1[sl][64 + j], gn = qgi1[sl][128 + j];
                float r = fsigmoid(gr + a0);
                float z = fsigmoid(gz + a1);
                float nn2 = tanhf(gn + r * a2);
                h = (1.f - z) * nn2 + z * h;
            }
        }
        __syncthreads();
    }
    if (wid == 3) hout[(size_t)n * HH + j] = h;
}

// ---------------- head: BN + relu + linear + log_softmax ----------------
__global__ __launch_bounds__(256) void k_head(const float* __restrict__ Hf,
                                              const float* __restrict__ g, const float* __restrict__ b,
                                              const float* __restrict__ m, const float* __restrict__ v,
                                              const float* __restrict__ W, const float* __restrict__ wb,
                                              float* __restrict__ out) {
    __shared__ float hb[4][HH];
    __shared__ float lg[4][CC];
    int tid = threadIdx.x;
    int n0 = blockIdx.x * 4;
    int wv = tid >> 6, lane = tid & 63;
    int n = n0 + wv;
    float x = Hf[(size_t)n * HH + lane];
    x = (x - m[lane]) * rsqrtf(v[lane] + EPSBN) * g[lane] + b[lane];
    hb[wv][lane] = fmaxf(x, 0.f);
    __syncthreads();
    if (tid < 4 * CC) {
        int nn = tid / CC, c = tid % CC;
        float acc = wb[c];
        for (int f = 0; f < HH; ++f) acc += hb[nn][f] * W[c * HH + f];
        lg[nn][c] = acc;
    }
    __syncthreads();
    if (tid < 4 * CC) {
        int nn = tid / CC, c = tid % CC;
        float mx = -1e30f;
#pragma unroll
        for (int i = 0; i < CC; ++i) mx = fmaxf(mx, lg[nn][i]);
        float s = 0.f;
#pragma unroll
        for (int i = 0; i < CC; ++i) s += __expf(lg[nn][i] - mx);
        out[(size_t)(n0 + nn) * CC + c] = lg[nn][c] - mx - __logf(s);
    }
}

// ---------------- launch ----------------
extern "C" void kernel_launch(void* const* d_in, const int* in_sizes, int n_in,
                              void* d_out, int out_size, void* d_ws, size_t ws_size,
                              hipStream_t stream) {
    const float* x_seq     = (const float*)d_in[0];
    const int*   edge_idx  = (const int*)d_in[1];
    const float* edge_w    = (const float*)d_in[2];
    const float* causal_w  = (const float*)d_in[3];
    const float* lin_in_w  = (const float*)d_in[4];
    const float* lin_in_b  = (const float*)d_in[5];
    const float* fusion_w  = (const float*)d_in[6];
    const float* fusion_b  = (const float*)d_in[7];
    const float* gcn_w0    = (const float*)d_in[8];
    const float* gcn_b0    = (const float*)d_in[9];
    const float* gcn_w1    = (const float*)d_in[10];
    const float* gcn_b1    = (const float*)d_in[11];
    const float* bn0_g = (const float*)d_in[12], *bn0_b = (const float*)d_in[13];
    const float* bn0_m = (const float*)d_in[14], *bn0_v = (const float*)d_in[15];
    const float* bn1_g = (const float*)d_in[16], *bn1_b = (const float*)d_in[17];
    const float* bn1_m = (const float*)d_in[18], *bn1_v = (const float*)d_in[19];
    const float* wih0 = (const float*)d_in[20], *whh0 = (const float*)d_in[21];
    const float* bih0 = (const float*)d_in[22], *bhh0 = (const float*)d_in[23];
    const float* wih1 = (const float*)d_in[24], *whh1 = (const float*)d_in[25];
    const float* bih1 = (const float*)d_in[26], *bhh1 = (const float*)d_in[27];
    const float* bno_g = (const float*)d_in[28], *bno_b = (const float*)d_in[29];
    const float* bno_m = (const float*)d_in[30], *bno_v = (const float*)d_in[31];
    const float* lout_w = (const float*)d_in[32], *lout_b = (const float*)d_in[33];
    float* out = (float*)d_out;

    float* wsf = (float*)d_ws;
    unsigned short* WCH = (unsigned short*)(wsf + OFF_WC);
    float* XA  = wsf + OFF_XA;
    float* XB  = wsf + OFF_XB;
    float* XC  = wsf + OFF_XC;
    unsigned short* XAT = (unsigned short*)(wsf + OFF_XC);
    unsigned short* XBH = (unsigned short*)(wsf + OFF_XB);   // bf16 x_agg (gemm C)
    float* DEG = wsf + OFF_DEG;
    int* CNT   = (int*)(wsf + OFF_CNT);
    int* CUR   = (int*)(wsf + OFF_CUR);
    int* OFFP  = (int*)(wsf + OFF_OFF);
    int* CSRS  = (int*)(wsf + OFF_CSRS);
    float* CSRN = wsf + OFF_CSRN;
    float* HST  = wsf + OFF_HST;

    // CSR + degree build
    k_zero<<<8, 256, 0, stream>>>(CNT, CUR, DEG);
    k_count<<<(ETOT + 255) / 256, 256, 0, stream>>>(edge_idx, edge_w, CNT, DEG);
    k_scan<<<1, 1024, 0, stream>>>(CNT, OFFP);
    k_fill<<<(ETOT + 255) / 256, 256, 0, stream>>>(edge_idx, edge_w, DEG, OFFP, CUR, CSRS, CSRN);

    hipMemsetAsync(WCH, 0, (size_t)2048 * 2048 * 2, stream);
    k_softmax<<<NN, 256, 0, stream>>>(causal_w, WCH);
    // lin_in -> XA [N,T,H] fp32
    k_lin2<<<NN, 256, 0, stream>>>(x_seq, lin_in_w, lin_in_b, XA);
    // transpose+cast: XA -> XAh_t bf16 [4096][2048]
    dim3 tg(THL / 64, 2048 / 64);
    k_tr<<<tg, 256, 0, stream>>>(XA, XAT);
    // x_agg = WCh @ X (MFMA bf16) -> XBH (bf16)
    dim3 gg(THL / 128, 2048 / 128);
    k_gemm_bf<<<gg, 256, 0, stream>>>(WCH, XAT, XBH);
    // fusion -> XC  (X fp32 + XAgg bf16)
    k_fus2<<<NN, 256, 0, stream>>>(XA, XBH, fusion_w, fusion_b, XC);
    // GCN layer 0: XC -> XB (xw) -> XA (agg+bn+relu)
    k_xw2<<<NN, 256, 0, stream>>>(XC, gcn_w0, XB);
    dim3 ag(NN, 4);
    k_agg<<<ag, 256, 0, stream>>>(XB, OFFP, CSRS, CSRN, gcn_b0, bn0_g, bn0_b, bn0_m, bn0_v, XA);
    // GCN layer 1: XA -> XB -> XC
    k_xw2<<<NN, 256, 0, stream>>>(XA, gcn_w1, XB);
    k_agg<<<ag, 256, 0, stream>>>(XB, OFFP, CSRS, CSRN, gcn_b1, bn1_g, bn1_b, bn1_m, bn1_v, XC);

    // 4-wave pipelined 2-layer GRU: XC -> final h in HST (single dispatch)
    k_gru4<<<NN, 256, 0, stream>>>(XC, wih0, whh0, bih0, bhh0,
                                   wih1, whh1, bih1, bhh1, HST);

    // head
    k_head<<<NN / 4, 256, 0, stream>>>(HST, bno_g, bno_b, bno_m, bno_v, lout_w, lout_b, out);
}